// Round 11
// baseline (1211.925 us; speedup 1.0000x reference)
//
#include <hip/hip_runtime.h>
#include <stdint.h>

// GRUClassifier: 2-layer bidir GRU (H=128, T=512, B=512) + FC head.
// R11: l1 scan role gets the R9/R10 treatment: BC=4 (256 scan blocks),
// shfl redistribution -> ONE gate element per lane (3 transcendentals + 3
// scalar G loads per step, was 12+12). Fused launch = 256 scan blocks +
// 24*CT gemm blocks co-resident (2 blocks/CU: LDS 78KB*2 fits 160KB).
// gemm role / gru_l0 / fc_head verbatim R10.

#define Tt 512
#define Bb 512
#define THREADS 512

using s16x8 = __attribute__((ext_vector_type(8))) short;  // 8 bf16 (4 VGPRs)
using f32x4 = __attribute__((ext_vector_type(4))) float;

#define MF(a, b, c) __builtin_amdgcn_mfma_f32_16x16x32_bf16((a), (b), (c), 0, 0, 0)

__device__ __forceinline__ unsigned short f2bf(float f) {
    union { float f; unsigned int u; } v; v.f = f;
    unsigned int u = v.u;
    u += 0x7fffu + ((u >> 16) & 1u);   // RNE
    return (unsigned short)(u >> 16);
}
__device__ __forceinline__ float bf2f(unsigned short h) {
    union { unsigned int u; float f; } v; v.u = ((unsigned int)h) << 16;
    return v.f;
}

__device__ __forceinline__ float fsig(float x) {
    return __builtin_amdgcn_rcpf(1.0f + __expf(-x));
}
__device__ __forceinline__ float ftanh(float x) {
    return 2.0f * __builtin_amdgcn_rcpf(1.0f + __expf(-2.0f * x)) - 1.0f;
}

// Raw workgroup barrier: drains LDS ops only; in-flight global register
// prefetch loads survive it (vmcnt not drained).
#define WG_BARRIER() asm volatile("s_waitcnt lgkmcnt(0)\n\ts_barrier" ::: "memory")

// ---------------------------------------------------------------------------
// w_prep: pack W_ih1 (both dirs) to bf16 [768][256] + bias concat [768].
// ---------------------------------------------------------------------------
__global__ void w_prep(const float* __restrict__ wihf, const float* __restrict__ wihb,
                       const float* __restrict__ bihf, const float* __restrict__ bihb,
                       unsigned short* __restrict__ wcat, float* __restrict__ bcat)
{
    const int n = blockIdx.x;   // 0..767
    const int k = threadIdx.x;  // 0..255
    const float* src = (n < 384) ? &wihf[(size_t)n * 256] : &wihb[(size_t)(n - 384) * 256];
    wcat[(size_t)n * 256 + k] = f2bf(src[k]);
    if (k == 0) bcat[n] = (n < 384) ? bihf[n] : bihb[n - 384];
}

// ---------------------------------------------------------------------------
// l1_step: fused chunk kernel.
//   blocks [0,nscan): scan role (BC=4: dir = bid>>7, chunk = bid&127).
//   blocks [nscan,..): gemm role, chunk kgemm, writes gx_wr.
//   gx layout [(dir*CT+sl)*512 + b]*384 + gc  (gc = gate*128 + col).
// ---------------------------------------------------------------------------
__global__ __launch_bounds__(THREADS) void l1_step(
    const unsigned short* __restrict__ y0,
    const unsigned short* __restrict__ wcat,
    const float* __restrict__ bcat,
    const unsigned short* __restrict__ gx_rd,
    unsigned short* __restrict__ gx_wr,
    const float* __restrict__ whh_f, const float* __restrict__ bhh_f,
    const float* __restrict__ whh_b, const float* __restrict__ bhh_b,
    float* __restrict__ hstate,
    int CT, int kgemm, int nscan, int first)
{
    const int bid  = blockIdx.x;
    const int tid  = threadIdx.x;
    const int wave = tid >> 6;
    const int lane = tid & 63;
    const int lcol = lane & 15;
    const int quad = lane >> 4;

    __shared__ __align__(16) unsigned short lA[128][136];
    __shared__ __align__(16) unsigned short lB[128][136];
    __shared__ __align__(16) unsigned short lds_h[2][16][136];

    if (bid >= nscan) {
        // =============================== GEMM role ===========================
        int gb = bid - nscan;
        const int nt = gb % 3;  gb /= 3;
        const int bt = gb & 3;  gb >>= 2;
        const int sl = gb % CT;
        const int dir = gb / CT;
        const int s  = kgemm * CT + sl;
        const int t  = dir ? (511 - s) : s;
        const int bb = bt << 7;

        const unsigned short* Abase = y0 + ((size_t)t * 512 + bb) * 256;
        const unsigned short* Bbase = wcat + ((size_t)dir * 384 + nt * 128) * 256;

        const int r0 = (wave >> 2) * 64;   // 0 or 64
        const int c0 = (wave & 3) * 32;    // 0,32,64,96

        f32x4 acc[4][2];
#pragma unroll
        for (int ti = 0; ti < 4; ++ti)
#pragma unroll
            for (int tj = 0; tj < 2; ++tj) acc[ti][tj] = {0.f, 0.f, 0.f, 0.f};

        const int rstg = tid >> 4;         // 0..31
        const int cstg = (tid & 15) * 8;   // 0..120 (<136)

#pragma unroll
        for (int kh = 0; kh < 2; ++kh) {
            if (kh) __syncthreads();
#pragma unroll
            for (int it = 0; it < 4; ++it) {
                const int r = it * 32 + rstg;
                *(ulonglong2*)&lA[r][cstg] =
                    *(const ulonglong2*)&Abase[(size_t)r * 256 + kh * 128 + cstg];
                *(ulonglong2*)&lB[r][cstg] =
                    *(const ulonglong2*)&Bbase[(size_t)r * 256 + kh * 128 + cstg];
            }
            __syncthreads();

#pragma unroll
            for (int kk = 0; kk < 4; ++kk) {
                s16x8 af[4], bfv[2];
#pragma unroll
                for (int ti = 0; ti < 4; ++ti)
                    af[ti] = *(const s16x8*)&lA[r0 + ti * 16 + lcol][kk * 32 + quad * 8];
#pragma unroll
                for (int tj = 0; tj < 2; ++tj)
                    bfv[tj] = *(const s16x8*)&lB[c0 + tj * 16 + lcol][kk * 32 + quad * 8];
#pragma unroll
                for (int ti = 0; ti < 4; ++ti)
#pragma unroll
                    for (int tj = 0; tj < 2; ++tj)
                        acc[ti][tj] = MF(af[ti], bfv[tj], acc[ti][tj]);
            }
        }

        float bias[2];
#pragma unroll
        for (int tj = 0; tj < 2; ++tj)
            bias[tj] = bcat[dir * 384 + nt * 128 + c0 + tj * 16 + lcol];

        __syncthreads();   // fragment reads done; reuse lA as C staging

        unsigned short* lC = &lA[0][0];
#pragma unroll
        for (int ti = 0; ti < 4; ++ti)
#pragma unroll
            for (int tj = 0; tj < 2; ++tj) {
                const int col = c0 + tj * 16 + lcol;
#pragma unroll
                for (int i = 0; i < 4; ++i)
                    lC[(size_t)(r0 + ti * 16 + 4 * quad + i) * 136 + col] =
                        f2bf(acc[ti][tj][i] + bias[tj]);
            }
        __syncthreads();

        unsigned short* ob = gx_wr + ((size_t)(dir * CT + sl) * 512 + bb) * 384 + nt * 128;
#pragma unroll
        for (int it = 0; it < 4; ++it) {
            const int r = it * 32 + rstg;
            *(ulonglong2*)&ob[(size_t)r * 384 + cstg] =
                *(const ulonglong2*)&lC[(size_t)r * 136 + cstg];
        }
        return;
    }

    // ============================ SCAN role (BC=4) ===========================
    const int dir   = bid >> 7;
    const int chunk = bid & 127;
    const int b0    = chunk * 4;
    const int c     = 16 * wave + lcol;

    const float* whh = dir ? whh_b : whh_f;
    const float* bhh = dir ? bhh_b : bhh_f;

    const float bhr = bhh[c];
    const float bhz = bhh[128 + c];
    const float bhn = bhh[256 + c];

    s16x8 bh[3][4];
#pragma unroll
    for (int p = 0; p < 3; ++p) {
        const int nrow = p * 128 + c;
#pragma unroll
        for (int kk = 0; kk < 4; ++kk) {
            const float* src = &whh[(size_t)nrow * 128 + kk * 32 + quad * 8];
            s16x8 f;
#pragma unroll
            for (int j = 0; j < 8; ++j) f[j] = (short)f2bf(src[j]);
            bh[p][kk] = f;
        }
    }

    // G loads: lane needs (row = b0+quad, col = c) for 3 gates.
    const unsigned short* gbase = gx_rd + (size_t)dir * CT * 512 * 384;
    auto loadGX = [&](unsigned short (&G)[3], int sl) {
        const unsigned short* gp = gbase + ((size_t)sl * 512 + b0 + quad) * 384;
#pragma unroll
        for (int g = 0; g < 3; ++g) G[g] = gp[g * 128 + c];
    };
    unsigned short G0[3], G1[3];
    loadGX(G0, 0);
    loadGX(G1, 1);

    // h init: zero LDS (rows 4..15 must stay zero), then rows 0..3 from state.
    float hmine;
    for (int idx = tid; idx < 2 * 16 * 136; idx += THREADS)
        ((unsigned short*)lds_h)[idx] = 0;
    __syncthreads();
    const int irow = tid >> 7, icol = tid & 127;
    if (first) {
        hmine = 0.f;
    } else {
        hmine = hstate[(size_t)(b0 + quad) * 256 + dir * 128 + c];
        lds_h[0][irow][icol] =
            f2bf(hstate[(size_t)(b0 + irow) * 256 + dir * 128 + icol]);
    }
    __syncthreads();

#define L1C_STEP(S, PAR, G)                                                    \
    do {                                                                       \
        const s16x8 a0 = *(const s16x8*)&lds_h[PAR][lcol][0  + quad * 8];      \
        const s16x8 a1 = *(const s16x8*)&lds_h[PAR][lcol][32 + quad * 8];      \
        const s16x8 a2 = *(const s16x8*)&lds_h[PAR][lcol][64 + quad * 8];      \
        const s16x8 a3 = *(const s16x8*)&lds_h[PAR][lcol][96 + quad * 8];      \
        f32x4 accr  = {bhr, bhr, bhr, bhr};                                    \
        f32x4 accz  = {bhz, bhz, bhz, bhz};                                    \
        f32x4 acchn = {bhn, bhn, bhn, bhn};                                    \
        accr = MF(a0, bh[0][0], accr); accz = MF(a0, bh[1][0], accz);          \
        acchn = MF(a0, bh[2][0], acchn);                                       \
        accr = MF(a1, bh[0][1], accr); accz = MF(a1, bh[1][1], accz);          \
        acchn = MF(a1, bh[2][1], acchn);                                       \
        accr = MF(a2, bh[0][2], accr); accz = MF(a2, bh[1][2], accz);          \
        acchn = MF(a2, bh[2][2], acchn);                                       \
        accr = MF(a3, bh[0][3], accr); accz = MF(a3, bh[1][3], accz);          \
        acchn = MF(a3, bh[2][3], acchn);                                       \
        /* redistribute: element (row i, col lcol) lives in lane lcol reg i */ \
        float rr0 = __shfl(accr[0], lcol), rr1 = __shfl(accr[1], lcol);        \
        float rr2 = __shfl(accr[2], lcol), rr3 = __shfl(accr[3], lcol);        \
        float zz0 = __shfl(accz[0], lcol), zz1 = __shfl(accz[1], lcol);        \
        float zz2 = __shfl(accz[2], lcol), zz3 = __shfl(accz[3], lcol);        \
        float hh0 = __shfl(acchn[0], lcol), hh1 = __shfl(acchn[1], lcol);      \
        float hh2 = __shfl(acchn[2], lcol), hh3 = __shfl(acchn[3], lcol);      \
        const float pr = quad == 0 ? rr0 : quad == 1 ? rr1 : quad == 2 ? rr2 : rr3; \
        const float pz = quad == 0 ? zz0 : quad == 1 ? zz1 : quad == 2 ? zz2 : zz3; \
        const float ph = quad == 0 ? hh0 : quad == 1 ? hh1 : quad == 2 ? hh2 : hh3; \
        {                                                                      \
            const float r = fsig(pr + bf2f(G[0]));                             \
            const float z = fsig(pz + bf2f(G[1]));                             \
            const float n = ftanh(bf2f(G[2]) + r * ph);                        \
            hmine = (1.0f - z) * n + z * hmine;                                \
            lds_h[PAR ^ 1][quad][c] = f2bf(hmine);                             \
        }                                                                      \
        if ((S) < CT - 2) {                                                    \
            loadGX(G, (S) + 2);                                                \
        } else if ((S) == CT - 1) {                                            \
            hstate[(size_t)(b0 + quad) * 256 + dir * 128 + c] = hmine;         \
        }                                                                      \
        WG_BARRIER();                                                          \
    } while (0)

    for (int sl = 0; sl < CT; sl += 2) {
        L1C_STEP(sl,     0, G0);
        L1C_STEP(sl + 1, 1, G1);
    }
#undef L1C_STEP
}

// ---------------------------------------------------------------------------
// Fallback layer-1 (fused Gx, verbatim from passing R3) — if no CT fits.
// ---------------------------------------------------------------------------
__global__ __launch_bounds__(THREADS, 1) void gru_l1(
    const unsigned short* __restrict__ y0,
    const float* __restrict__ wih_f, const float* __restrict__ whh_f,
    const float* __restrict__ bih_f, const float* __restrict__ bhh_f,
    const float* __restrict__ wih_b, const float* __restrict__ whh_b,
    const float* __restrict__ bih_b, const float* __restrict__ bhh_b,
    float* __restrict__ finals)
{
    const int tid  = threadIdx.x;
    const int wave = tid >> 6;
    const int lane = tid & 63;
    const int lcol = lane & 15;
    const int quad = lane >> 4;
    const int dir   = blockIdx.x >> 5;
    const int b0    = (blockIdx.x & 31) * 16;
    const int c     = 16 * wave + lcol;

    const float* wih = dir ? wih_b : wih_f;
    const float* whh = dir ? whh_b : whh_f;
    const float* bih = dir ? bih_b : bih_f;
    const float* bhh = dir ? bhh_b : bhh_f;

    __shared__ __align__(16) unsigned short lds_h[2][16][136];

    const float br  = bih[c]       + bhh[c];
    const float bz  = bih[128 + c] + bhh[128 + c];
    const float bnx = bih[256 + c];
    const float bnh = bhh[256 + c];

    s16x8 bh[3][4];
    s16x8 bx[3][8];
#pragma unroll
    for (int p = 0; p < 3; ++p) {
        const int nrow = p * 128 + c;
#pragma unroll
        for (int kk = 0; kk < 4; ++kk) {
            const float* src = &whh[(size_t)nrow * 128 + kk * 32 + quad * 8];
            s16x8 f;
#pragma unroll
            for (int j = 0; j < 8; ++j) f[j] = (short)f2bf(src[j]);
            bh[p][kk] = f;
        }
#pragma unroll
        for (int kk = 0; kk < 8; ++kk) {
            const float* src = &wih[(size_t)nrow * 256 + kk * 32 + quad * 8];
            s16x8 f;
#pragma unroll
            for (int j = 0; j < 8; ++j) f[j] = (short)f2bf(src[j]);
            bx[p][kk] = f;
        }
    }

    auto loadP = [&](s16x8 (&P)[8], int t) {
        const unsigned short* pb = y0 + ((size_t)t * Bb + b0 + lcol) * 256 + quad * 8;
#pragma unroll
        for (int kk = 0; kk < 8; ++kk) P[kk] = *(const s16x8*)(pb + kk * 32);
    };
    s16x8 P0[8], P1[8];
    loadP(P0, dir ? 511 : 0);
    loadP(P1, dir ? 510 : 1);

    f32x4 accr = {br, br, br, br};
    f32x4 accz = {bz, bz, bz, bz};
    f32x4 accnx = {bnx, bnx, bnx, bnx};
#pragma unroll
    for (int kk = 0; kk < 8; ++kk) {
        accr  = MF(P0[kk], bx[0][kk], accr);
        accz  = MF(P0[kk], bx[1][kk], accz);
        accnx = MF(P0[kk], bx[2][kk], accnx);
    }
    loadP(P0, dir ? 509 : 2);

    float hreg[4] = {0.f, 0.f, 0.f, 0.f};
    for (int idx = tid; idx < 2 * 16 * 136; idx += THREADS)
        ((unsigned short*)lds_h)[idx] = 0;
    __syncthreads();

#define L1_STEP(S, PAR, PN)                                                    \
    do {                                                                       \
        const s16x8 a0 = *(const s16x8*)&lds_h[PAR][lcol][0  + quad * 8];      \
        const s16x8 a1 = *(const s16x8*)&lds_h[PAR][lcol][32 + quad * 8];      \
        const s16x8 a2 = *(const s16x8*)&lds_h[PAR][lcol][64 + quad * 8];      \
        const s16x8 a3 = *(const s16x8*)&lds_h[PAR][lcol][96 + quad * 8];      \
        f32x4 acchn = {bnh, bnh, bnh, bnh};                                    \
        accr = MF(a0, bh[0][0], accr); accz = MF(a0, bh[1][0], accz);          \
        acchn = MF(a0, bh[2][0], acchn);                                       \
        accr = MF(a1, bh[0][1], accr); accz = MF(a1, bh[1][1], accz);          \
        acchn = MF(a1, bh[2][1], acchn);                                       \
        accr = MF(a2, bh[0][2], accr); accz = MF(a2, bh[1][2], accz);          \
        acchn = MF(a2, bh[2][2], acchn);                                       \
        accr = MF(a3, bh[0][3], accr); accz = MF(a3, bh[1][3], accz);          \
        acchn = MF(a3, bh[2][3], acchn);                                       \
        _Pragma("unroll")                                                      \
        for (int i = 0; i < 4; ++i) {                                          \
            const float r = fsig(accr[i]);                                     \
            const float z = fsig(accz[i]);                                     \
            const float n = ftanh(accnx[i] + r * acchn[i]);                    \
            hreg[i] = (1.0f - z) * n + z * hreg[i];                            \
            lds_h[PAR ^ 1][4 * quad + i][c] = f2bf(hreg[i]);                   \
        }                                                                      \
        if ((S) < 511) {                                                       \
            accr = {br, br, br, br}; accz = {bz, bz, bz, bz};                  \
            accnx = {bnx, bnx, bnx, bnx};                                      \
            _Pragma("unroll")                                                  \
            for (int kk = 0; kk < 8; ++kk) {                                   \
                accr  = MF(PN[kk], bx[0][kk], accr);                           \
                accz  = MF(PN[kk], bx[1][kk], accz);                           \
                accnx = MF(PN[kk], bx[2][kk], accnx);                          \
            }                                                                  \
            int sp = (S) + 3; if (sp > 511) sp = 511;                          \
            loadP(PN, dir ? (511 - sp) : sp);                                  \
        } else {                                                               \
            _Pragma("unroll")                                                  \
            for (int i = 0; i < 4; ++i)                                        \
                finals[(size_t)(b0 + 4 * quad + i) * 256 + dir * 128 + c] =    \
                    hreg[i];                                                   \
        }                                                                      \
        WG_BARRIER();                                                          \
    } while (0)

    for (int s = 0; s < Tt; s += 2) {
        L1_STEP(s,     0, P1);
        L1_STEP(s + 1, 1, P0);
    }
#undef L1_STEP
}

// ---------------------------------------------------------------------------
// Layer 0 scan (verbatim R10): BC=4, bias-only MFMA init, shfl redistribution,
// own-row x-projection after redistribution.
// ---------------------------------------------------------------------------
__global__ __launch_bounds__(THREADS, 1) void gru_l0(
    const float* __restrict__ x,
    const float* __restrict__ wih_f, const float* __restrict__ whh_f,
    const float* __restrict__ bih_f, const float* __restrict__ bhh_f,
    const float* __restrict__ wih_b, const float* __restrict__ whh_b,
    const float* __restrict__ bih_b, const float* __restrict__ bhh_b,
    unsigned short* __restrict__ y0)
{
    const int tid  = threadIdx.x;
    const int wave = tid >> 6;
    const int lane = tid & 63;
    const int lcol = lane & 15;
    const int quad = lane >> 4;
    const int dir   = blockIdx.x >> 7;
    const int chunk = blockIdx.x & 127;
    const int b0    = chunk * 4;
    const int c     = 16 * wave + lcol;

    const float* wih = dir ? wih_b : wih_f;
    const float* whh = dir ? whh_b : whh_f;
    const float* bih = dir ? bih_b : bih_f;
    const float* bhh = dir ? bhh_b : bhh_f;

    __shared__ __align__(16) unsigned short lds_h[2][16][136];

    const float brs  = bih[c]       + bhh[c];
    const float bzs  = bih[128 + c] + bhh[128 + c];
    const float bnxs = bih[256 + c];
    const float bnh  = bhh[256 + c];

    float wr[4], wz[4], wn[4];
#pragma unroll
    for (int f = 0; f < 4; ++f) {
        wr[f] = wih[(c)       * 4 + f];
        wz[f] = wih[(128 + c) * 4 + f];
        wn[f] = wih[(256 + c) * 4 + f];
    }

    s16x8 bh[3][4];
#pragma unroll
    for (int p = 0; p < 3; ++p) {
        const int nrow = p * 128 + c;
#pragma unroll
        for (int kk = 0; kk < 4; ++kk) {
            const float* src = &whh[(size_t)nrow * 128 + kk * 32 + quad * 8];
            s16x8 f;
#pragma unroll
            for (int j = 0; j < 8; ++j) f[j] = (short)f2bf(src[j]);
            bh[p][kk] = f;
        }
    }

    auto loadX = [&](float4& X, int t) {
        X = *(const float4*)&x[((size_t)(b0 + quad) * Tt + t) * 4];
    };
    float4 X0, X1;
    loadX(X0, dir ? 511 : 0);
    loadX(X1, dir ? 510 : 1);

    float hmine = 0.f;   // this lane's h element: (row=quad, col=c)
    for (int idx = tid; idx < 2 * 16 * 136; idx += THREADS)
        ((unsigned short*)lds_h)[idx] = 0;
    __syncthreads();

    const int orow = tid >> 7;        // y0 store: row 0..3
    const int ocol = tid & 127;       // col 0..127

#define L0_STEP(S, PAR, XC)                                                    \
    do {                                                                       \
        const int t = dir ? (511 - (S)) : (S);                                 \
        const s16x8 a0 = *(const s16x8*)&lds_h[PAR][lcol][0  + quad * 8];      \
        const s16x8 a1 = *(const s16x8*)&lds_h[PAR][lcol][32 + quad * 8];      \
        const s16x8 a2 = *(const s16x8*)&lds_h[PAR][lcol][64 + quad * 8];      \
        const s16x8 a3 = *(const s16x8*)&lds_h[PAR][lcol][96 + quad * 8];      \
        f32x4 accr  = {brs, brs, brs, brs};                                    \
        f32x4 accz  = {bzs, bzs, bzs, bzs};                                    \
        f32x4 acchn = {bnh, bnh, bnh, bnh};                                    \
        accr = MF(a0, bh[0][0], accr); accz = MF(a0, bh[1][0], accz);          \
        acchn = MF(a0, bh[2][0], acchn);                                       \
        accr = MF(a1, bh[0][1], accr); accz = MF(a1, bh[1][1], accz);          \
        acchn = MF(a1, bh[2][1], acchn);                                       \
        accr = MF(a2, bh[0][2], accr); accz = MF(a2, bh[1][2], accz);          \
        acchn = MF(a2, bh[2][2], acchn);                                       \
        accr = MF(a3, bh[0][3], accr); accz = MF(a3, bh[1][3], accz);          \
        acchn = MF(a3, bh[2][3], acchn);                                       \
        const float xr = XC.x * wr[0] + XC.y * wr[1]                           \
                       + XC.z * wr[2] + XC.w * wr[3];                          \
        const float xz = XC.x * wz[0] + XC.y * wz[1]                           \
                       + XC.z * wz[2] + XC.w * wz[3];                          \
        const float xn = bnxs + XC.x * wn[0] + XC.y * wn[1]                    \
                       + XC.z * wn[2] + XC.w * wn[3];                          \
        float rr0 = __shfl(accr[0], lcol), rr1 = __shfl(accr[1], lcol);        \
        float rr2 = __shfl(accr[2], lcol), rr3 = __shfl(accr[3], lcol);        \
        float zz0 = __shfl(accz[0], lcol), zz1 = __shfl(accz[1], lcol);        \
        float zz2 = __shfl(accz[2], lcol), zz3 = __shfl(accz[3], lcol);        \
        float hh0 = __shfl(acchn[0], lcol), hh1 = __shfl(acchn[1], lcol);      \
        float hh2 = __shfl(acchn[2], lcol), hh3 = __shfl(acchn[3], lcol);      \
        const float pr = quad == 0 ? rr0 : quad == 1 ? rr1 : quad == 2 ? rr2 : rr3; \
        const float pz = quad == 0 ? zz0 : quad == 1 ? zz1 : quad == 2 ? zz2 : zz3; \
        const float ph = quad == 0 ? hh0 : quad == 1 ? hh1 : quad == 2 ? hh2 : hh3; \
        {                                                                      \
            const float r = fsig(pr + xr);                                     \
            const float z = fsig(pz + xz);                                     \
            const float n = ftanh(xn + r * ph);                                \
            hmine = (1.0f - z) * n + z * hmine;                                \
            lds_h[PAR ^ 1][quad][c] = f2bf(hmine);                             \
        }                                                                      \
        if ((S) < 510) {                                                       \
            loadX(XC, dir ? (511 - ((S) + 2)) : ((S) + 2));                    \
        }                                                                      \
        WG_BARRIER();                                                          \
        {                                                                      \
            y0[((size_t)t * Bb + b0 + orow) * 256 + dir * 128 + ocol] =        \
                lds_h[PAR ^ 1][orow][ocol];                                    \
        }                                                                      \
    } while (0)

    for (int s = 0; s < Tt; s += 2) {
        L0_STEP(s,     0, X0);
        L0_STEP(s + 1, 1, X1);
    }
#undef L0_STEP
}

// ---------------------------------------------------------------------------
// FC head: out = relu(finals @ fc1^T + b1) @ fc2^T + b2   [512,256]->[512,2]
// ---------------------------------------------------------------------------
__global__ __launch_bounds__(128) void fc_head(
    const float* __restrict__ finals,
    const float* __restrict__ fc1w, const float* __restrict__ fc1b,
    const float* __restrict__ fc2w, const float* __restrict__ fc2b,
    float* __restrict__ out)
{
    __shared__ float s_in[256];
    __shared__ float s_h1[128];
    const int b = blockIdx.x, tid = threadIdx.x;
    s_in[tid]       = finals[(size_t)b * 256 + tid];
    s_in[tid + 128] = finals[(size_t)b * 256 + 128 + tid];
    __syncthreads();
    float acc = fc1b[tid];
    const float* wrow = &fc1w[tid * 256];
#pragma unroll 8
    for (int i = 0; i < 256; ++i) acc += s_in[i] * wrow[i];
    s_h1[tid] = fmaxf(acc, 0.0f);
    __syncthreads();
    if (tid < 2) {
        float a = fc2b[tid];
        const float* w2 = &fc2w[tid * 128];
#pragma unroll 8
        for (int i = 0; i < 128; ++i) a += s_h1[i] * w2[i];
        out[b * 2 + tid] = a;
    }
}

extern "C" void kernel_launch(void* const* d_in, const int* in_sizes, int n_in,
                              void* d_out, int out_size, void* d_ws, size_t ws_size,
                              hipStream_t stream) {
    const float* x      = (const float*)d_in[0];
    const float* wih0f  = (const float*)d_in[1];
    const float* whh0f  = (const float*)d_in[2];
    const float* bih0f  = (const float*)d_in[3];
    const float* bhh0f  = (const float*)d_in[4];
    const float* wih0b  = (const float*)d_in[5];
    const float* whh0b  = (const float*)d_in[6];
    const float* bih0b  = (const float*)d_in[7];
    const float* bhh0b  = (const float*)d_in[8];
    const float* wih1f  = (const float*)d_in[9];
    const float* whh1f  = (const float*)d_in[10];
    const float* bih1f  = (const float*)d_in[11];
    const float* bhh1f  = (const float*)d_in[12];
    const float* wih1b  = (const float*)d_in[13];
    const float* whh1b  = (const float*)d_in[14];
    const float* bih1b  = (const float*)d_in[15];
    const float* bhh1b  = (const float*)d_in[16];
    const float* fc1w   = (const float*)d_in[17];
    const float* fc1b   = (const float*)d_in[18];
    const float* fc2w   = (const float*)d_in[19];
    const float* fc2b   = (const float*)d_in[20];

    const size_t Y0SZ = 134217728ull;   // y0 bf16 [512][512][256]
    const size_t HSSZ = 524288ull;      // hstate/finals f32 [512][256]
    const size_t WCSZ = 393216ull;      // wcat bf16 [768][256]
    const size_t BCSZ = 3072ull;        // bcat f32 [768]
    const size_t GX_PER_SL = 786432ull; // per sl: 2 dirs * 512 * 384 bf16 * 2B
    const size_t BASE = Y0SZ + HSSZ + WCSZ + BCSZ;

    unsigned short* y0 = (unsigned short*)d_ws;
    float*  hstate = (float*)((char*)d_ws + Y0SZ);
    unsigned short* wcat = (unsigned short*)((char*)d_ws + Y0SZ + HSSZ);
    float*  bcat   = (float*)((char*)d_ws + Y0SZ + HSSZ + WCSZ);
    unsigned short* gx0 = (unsigned short*)((char*)d_ws + BASE);
    float* out = (float*)d_out;

    const int cts[6] = {128, 64, 32, 16, 8, 4};
    int CT = 0, fused = 0;
    for (int i = 0; i < 6; ++i)
        if (BASE + 2ull * cts[i] * GX_PER_SL <= ws_size) { CT = cts[i]; fused = 1; break; }
    if (!CT)
        for (int i = 0; i < 6; ++i)
            if (BASE + (size_t)cts[i] * GX_PER_SL <= ws_size) { CT = cts[i]; break; }

    if (CT > 0) {
        unsigned short* gxb[2];
        gxb[0] = gx0;
        gxb[1] = fused ? (unsigned short*)((char*)gx0 + (size_t)CT * GX_PER_SL) : gx0;

        w_prep<<<dim3(768), dim3(256), 0, stream>>>(wih1f, wih1b, bih1f, bih1b, wcat, bcat);
        gru_l0<<<dim3(256), dim3(THREADS), 0, stream>>>(
            x, wih0f, whh0f, bih0f, bhh0f, wih0b, whh0b, bih0b, bhh0b, y0);
        const int n = Tt / CT;
        if (fused) {
            // prologue: gemm chunk 0 -> buf0
            l1_step<<<dim3(24 * CT), dim3(THREADS), 0, stream>>>(
                y0, wcat, bcat, gxb[0], gxb[0],
                whh1f, bhh1f, whh1b, bhh1b, hstate, CT, 0, 0, 1);
            for (int k = 0; k < n; ++k) {
                const int ng = (k + 1 < n) ? 24 * CT : 0;
                l1_step<<<dim3(256 + ng), dim3(THREADS), 0, stream>>>(
                    y0, wcat, bcat, gxb[k & 1], gxb[(k + 1) & 1],
                    whh1f, bhh1f, whh1b, bhh1b, hstate, CT, k + 1, 256, (k == 0) ? 1 : 0);
            }
        } else {
            for (int k = 0; k < n; ++k) {
                l1_step<<<dim3(24 * CT), dim3(THREADS), 0, stream>>>(
                    y0, wcat, bcat, gxb[0], gxb[0],
                    whh1f, bhh1f, whh1b, bhh1b, hstate, CT, k, 0, 1);
                l1_step<<<dim3(256), dim3(THREADS), 0, stream>>>(
                    y0, wcat, bcat, gxb[0], gxb[0],
                    whh1f, bhh1f, whh1b, bhh1b, hstate, CT, 0, 256, (k == 0) ? 1 : 0);
            }
        }
        fc_head<<<dim3(Bb), dim3(128), 0, stream>>>(hstate, fc1w, fc1b, fc2w, fc2b, out);
    } else {
        float* finals = (float*)((char*)d_ws + Y0SZ);
        gru_l0<<<dim3(256), dim3(THREADS), 0, stream>>>(
            x, wih0f, whh0f, bih0f, bhh0f, wih0b, whh0b, bih0b, bhh0b, y0);
        gru_l1<<<dim3(64), dim3(THREADS), 0, stream>>>(
            y0, wih1f, whh1f, bih1f, bhh1f, wih1b, whh1b, bih1b, bhh1b, finals);
        fc_head<<<dim3(Bb), dim3(128), 0, stream>>>(finals, fc1w, fc1b, fc2w, fc2b, out);
    }
}

// Round 12
// 1148.793 us; speedup vs baseline: 1.0550x; 1.0550x over previous
//
#include <hip/hip_runtime.h>
#include <stdint.h>

// GRUClassifier: 2-layer bidir GRU (H=128, T=512, B=512) + FC head.
// R12 = R10 base (best: 1100us) + two contained changes:
//  (1) l1_step LDS padded to 82,688 B (>160K/2) -> exactly 1 block/CU, so the
//      64 scan blocks get EXCLUSIVE CUs (R10/R11 showed gemm co-residency on
//      scan CUs inflates the latency-bound scan step). Gemm uses the other
//      192 CUs via dynamic dispatch; its ~0.7x single-slot throughput still
//      hides under the scan chunk.
//  (2) gru_l0 MFMA dual accumulation chains (dep depth 4->2), summed before
//      the shfl redistribution (shfl count unchanged).

#define Tt 512
#define Bb 512
#define THREADS 512

using s16x8 = __attribute__((ext_vector_type(8))) short;  // 8 bf16 (4 VGPRs)
using f32x4 = __attribute__((ext_vector_type(4))) float;

#define MF(a, b, c) __builtin_amdgcn_mfma_f32_16x16x32_bf16((a), (b), (c), 0, 0, 0)

__device__ __forceinline__ unsigned short f2bf(float f) {
    union { float f; unsigned int u; } v; v.f = f;
    unsigned int u = v.u;
    u += 0x7fffu + ((u >> 16) & 1u);   // RNE
    return (unsigned short)(u >> 16);
}
__device__ __forceinline__ float bf2f(unsigned short h) {
    union { unsigned int u; float f; } v; v.u = ((unsigned int)h) << 16;
    return v.f;
}

__device__ __forceinline__ float fsig(float x) {
    return __builtin_amdgcn_rcpf(1.0f + __expf(-x));
}
__device__ __forceinline__ float ftanh(float x) {
    return 2.0f * __builtin_amdgcn_rcpf(1.0f + __expf(-2.0f * x)) - 1.0f;
}

// Raw workgroup barrier: drains LDS ops only; in-flight global register
// prefetch loads survive it (vmcnt not drained).
#define WG_BARRIER() asm volatile("s_waitcnt lgkmcnt(0)\n\ts_barrier" ::: "memory")

// ---------------------------------------------------------------------------
// w_prep: pack W_ih1 (both dirs) to bf16 [768][256] + bias concat [768].
// ---------------------------------------------------------------------------
__global__ void w_prep(const float* __restrict__ wihf, const float* __restrict__ wihb,
                       const float* __restrict__ bihf, const float* __restrict__ bihb,
                       unsigned short* __restrict__ wcat, float* __restrict__ bcat)
{
    const int n = blockIdx.x;   // 0..767
    const int k = threadIdx.x;  // 0..255
    const float* src = (n < 384) ? &wihf[(size_t)n * 256] : &wihb[(size_t)(n - 384) * 256];
    wcat[(size_t)n * 256 + k] = f2bf(src[k]);
    if (k == 0) bcat[n] = (n < 384) ? bihf[n] : bihb[n - 384];
}

// ---------------------------------------------------------------------------
// l1_step: fused chunk kernel (R10 structure; LDS padded for 1 block/CU).
//   blocks [0,nscan): scan role (BC=16), reads gx_rd.
//   blocks [nscan,..): gemm role, chunk kgemm, writes gx_wr.
//   gx layout [(dir*CT+sl)*512 + b]*384 + gc  (gc = gate*128 + col).
// ---------------------------------------------------------------------------
__global__ __launch_bounds__(THREADS) void l1_step(
    const unsigned short* __restrict__ y0,
    const unsigned short* __restrict__ wcat,
    const float* __restrict__ bcat,
    const unsigned short* __restrict__ gx_rd,
    unsigned short* __restrict__ gx_wr,
    const float* __restrict__ whh_f, const float* __restrict__ bhh_f,
    const float* __restrict__ whh_b, const float* __restrict__ bhh_b,
    float* __restrict__ hstate,
    int CT, int kgemm, int nscan, int first)
{
    const int bid  = blockIdx.x;
    const int tid  = threadIdx.x;
    const int wave = tid >> 6;
    const int lane = tid & 63;
    const int lcol = lane & 15;
    const int quad = lane >> 4;

    // 136-row declarations (rows >=128 unused): total static LDS = 82,688 B
    // > 81,920 B = 160K/2  =>  exactly 1 block/CU (scan CUs exclusive).
    __shared__ __align__(16) unsigned short lA[136][136];
    __shared__ __align__(16) unsigned short lB[136][136];
    __shared__ __align__(16) unsigned short lds_h[2][16][136];

    if (bid >= nscan) {
        // =============================== GEMM role ===========================
        int gb = bid - nscan;
        const int nt = gb % 3;  gb /= 3;
        const int bt = gb & 3;  gb >>= 2;
        const int sl = gb % CT;
        const int dir = gb / CT;
        const int s  = kgemm * CT + sl;
        const int t  = dir ? (511 - s) : s;
        const int bb = bt << 7;

        const unsigned short* Abase = y0 + ((size_t)t * 512 + bb) * 256;
        const unsigned short* Bbase = wcat + ((size_t)dir * 384 + nt * 128) * 256;

        const int r0 = (wave >> 2) * 64;   // 0 or 64
        const int c0 = (wave & 3) * 32;    // 0,32,64,96

        f32x4 acc[4][2];
#pragma unroll
        for (int ti = 0; ti < 4; ++ti)
#pragma unroll
            for (int tj = 0; tj < 2; ++tj) acc[ti][tj] = {0.f, 0.f, 0.f, 0.f};

        const int rstg = tid >> 4;         // 0..31
        const int cstg = (tid & 15) * 8;   // 0..120 (<136)

#pragma unroll
        for (int kh = 0; kh < 2; ++kh) {
            if (kh) __syncthreads();
#pragma unroll
            for (int it = 0; it < 4; ++it) {
                const int r = it * 32 + rstg;
                *(ulonglong2*)&lA[r][cstg] =
                    *(const ulonglong2*)&Abase[(size_t)r * 256 + kh * 128 + cstg];
                *(ulonglong2*)&lB[r][cstg] =
                    *(const ulonglong2*)&Bbase[(size_t)r * 256 + kh * 128 + cstg];
            }
            __syncthreads();

#pragma unroll
            for (int kk = 0; kk < 4; ++kk) {
                s16x8 af[4], bfv[2];
#pragma unroll
                for (int ti = 0; ti < 4; ++ti)
                    af[ti] = *(const s16x8*)&lA[r0 + ti * 16 + lcol][kk * 32 + quad * 8];
#pragma unroll
                for (int tj = 0; tj < 2; ++tj)
                    bfv[tj] = *(const s16x8*)&lB[c0 + tj * 16 + lcol][kk * 32 + quad * 8];
#pragma unroll
                for (int ti = 0; ti < 4; ++ti)
#pragma unroll
                    for (int tj = 0; tj < 2; ++tj)
                        acc[ti][tj] = MF(af[ti], bfv[tj], acc[ti][tj]);
            }
        }

        float bias[2];
#pragma unroll
        for (int tj = 0; tj < 2; ++tj)
            bias[tj] = bcat[dir * 384 + nt * 128 + c0 + tj * 16 + lcol];

        __syncthreads();   // fragment reads done; reuse lA as C staging

        unsigned short* lC = &lA[0][0];
#pragma unroll
        for (int ti = 0; ti < 4; ++ti)
#pragma unroll
            for (int tj = 0; tj < 2; ++tj) {
                const int col = c0 + tj * 16 + lcol;
#pragma unroll
                for (int i = 0; i < 4; ++i)
                    lC[(size_t)(r0 + ti * 16 + 4 * quad + i) * 136 + col] =
                        f2bf(acc[ti][tj][i] + bias[tj]);
            }
        __syncthreads();

        unsigned short* ob = gx_wr + ((size_t)(dir * CT + sl) * 512 + bb) * 384 + nt * 128;
#pragma unroll
        for (int it = 0; it < 4; ++it) {
            const int r = it * 32 + rstg;
            *(ulonglong2*)&ob[(size_t)r * 384 + cstg] =
                *(const ulonglong2*)&lC[(size_t)r * 136 + cstg];
        }
        return;
    }

    // ============================ SCAN role (BC=16) ==========================
    const int dir   = bid >> 5;
    const int chunk = bid & 31;
    const int b0    = chunk * 16;
    const int c     = 16 * wave + lcol;

    const float* whh = dir ? whh_b : whh_f;
    const float* bhh = dir ? bhh_b : bhh_f;

    const float bhr = bhh[c];
    const float bhz = bhh[128 + c];
    const float bhn = bhh[256 + c];

    s16x8 bh[3][4];
#pragma unroll
    for (int p = 0; p < 3; ++p) {
        const int nrow = p * 128 + c;
#pragma unroll
        for (int kk = 0; kk < 4; ++kk) {
            const float* src = &whh[(size_t)nrow * 128 + kk * 32 + quad * 8];
            s16x8 f;
#pragma unroll
            for (int j = 0; j < 8; ++j) f[j] = (short)f2bf(src[j]);
            bh[p][kk] = f;
        }
    }

    const unsigned short* gbase = gx_rd + (size_t)dir * CT * 512 * 384;
    auto loadGX = [&](unsigned short (&G)[12], int sl) {
        const unsigned short* gp = gbase + ((size_t)sl * 512 + b0 + 4 * quad) * 384;
#pragma unroll
        for (int g = 0; g < 3; ++g)
#pragma unroll
            for (int i = 0; i < 4; ++i)
                G[g * 4 + i] = gp[(size_t)i * 384 + g * 128 + c];
    };
    unsigned short G0[12], G1[12];
    loadGX(G0, 0);
    loadGX(G1, 1);

    float hreg[4];
    const int gb2 = tid >> 5;          // 0..15 batch row for LDS init
    const int j0  = (tid & 31) * 4;    // 0..124
    if (first) {
#pragma unroll
        for (int i = 0; i < 4; ++i) hreg[i] = 0.f;
        ushort4 z4; z4.x = 0; z4.y = 0; z4.z = 0; z4.w = 0;
        *(ushort4*)&lds_h[0][gb2][j0] = z4;
    } else {
#pragma unroll
        for (int i = 0; i < 4; ++i)
            hreg[i] = hstate[(size_t)(b0 + 4 * quad + i) * 256 + dir * 128 + c];
        ushort4 hv;
        hv.x = f2bf(hstate[(size_t)(b0 + gb2) * 256 + dir * 128 + j0 + 0]);
        hv.y = f2bf(hstate[(size_t)(b0 + gb2) * 256 + dir * 128 + j0 + 1]);
        hv.z = f2bf(hstate[(size_t)(b0 + gb2) * 256 + dir * 128 + j0 + 2]);
        hv.w = f2bf(hstate[(size_t)(b0 + gb2) * 256 + dir * 128 + j0 + 3]);
        *(ushort4*)&lds_h[0][gb2][j0] = hv;
    }
    __syncthreads();

#define L1C_STEP(S, PAR, G)                                                    \
    do {                                                                       \
        const s16x8 a0 = *(const s16x8*)&lds_h[PAR][lcol][0  + quad * 8];      \
        const s16x8 a1 = *(const s16x8*)&lds_h[PAR][lcol][32 + quad * 8];      \
        const s16x8 a2 = *(const s16x8*)&lds_h[PAR][lcol][64 + quad * 8];      \
        const s16x8 a3 = *(const s16x8*)&lds_h[PAR][lcol][96 + quad * 8];      \
        f32x4 rA = {bhr, bhr, bhr, bhr}, rB = {0.f, 0.f, 0.f, 0.f};            \
        f32x4 zA = {bhz, bhz, bhz, bhz}, zB = {0.f, 0.f, 0.f, 0.f};            \
        f32x4 nA = {bhn, bhn, bhn, bhn}, nB = {0.f, 0.f, 0.f, 0.f};            \
        rA = MF(a0, bh[0][0], rA); zA = MF(a0, bh[1][0], zA);                  \
        nA = MF(a0, bh[2][0], nA);                                             \
        rB = MF(a1, bh[0][1], rB); zB = MF(a1, bh[1][1], zB);                  \
        nB = MF(a1, bh[2][1], nB);                                             \
        rA = MF(a2, bh[0][2], rA); zA = MF(a2, bh[1][2], zA);                  \
        nA = MF(a2, bh[2][2], nA);                                             \
        rB = MF(a3, bh[0][3], rB); zB = MF(a3, bh[1][3], zB);                  \
        nB = MF(a3, bh[2][3], nB);                                             \
        _Pragma("unroll")                                                      \
        for (int i = 0; i < 4; ++i) {                                          \
            const float r = fsig(rA[i] + rB[i] + bf2f(G[i]));                  \
            const float z = fsig(zA[i] + zB[i] + bf2f(G[4 + i]));              \
            const float n = ftanh(bf2f(G[8 + i]) + r * (nA[i] + nB[i]));       \
            hreg[i] = (1.0f - z) * n + z * hreg[i];                            \
            lds_h[PAR ^ 1][4 * quad + i][c] = f2bf(hreg[i]);                   \
        }                                                                      \
        if ((S) < CT - 2) {                                                    \
            loadGX(G, (S) + 2);                                                \
        } else if ((S) == CT - 1) {                                            \
            _Pragma("unroll")                                                  \
            for (int i = 0; i < 4; ++i)                                        \
                hstate[(size_t)(b0 + 4 * quad + i) * 256 + dir * 128 + c] =    \
                    hreg[i];                                                   \
        }                                                                      \
        WG_BARRIER();                                                          \
    } while (0)

    for (int sl = 0; sl < CT; sl += 2) {
        L1C_STEP(sl,     0, G0);
        L1C_STEP(sl + 1, 1, G1);
    }
#undef L1C_STEP
}

// ---------------------------------------------------------------------------
// Fallback layer-1 (fused Gx, verbatim from passing R3) — if no CT fits.
// ---------------------------------------------------------------------------
__global__ __launch_bounds__(THREADS, 1) void gru_l1(
    const unsigned short* __restrict__ y0,
    const float* __restrict__ wih_f, const float* __restrict__ whh_f,
    const float* __restrict__ bih_f, const float* __restrict__ bhh_f,
    const float* __restrict__ wih_b, const float* __restrict__ whh_b,
    const float* __restrict__ bih_b, const float* __restrict__ bhh_b,
    float* __restrict__ finals)
{
    const int tid  = threadIdx.x;
    const int wave = tid >> 6;
    const int lane = tid & 63;
    const int lcol = lane & 15;
    const int quad = lane >> 4;
    const int dir   = blockIdx.x >> 5;
    const int b0    = (blockIdx.x & 31) * 16;
    const int c     = 16 * wave + lcol;

    const float* wih = dir ? wih_b : wih_f;
    const float* whh = dir ? whh_b : whh_f;
    const float* bih = dir ? bih_b : bih_f;
    const float* bhh = dir ? bhh_b : bhh_f;

    __shared__ __align__(16) unsigned short lds_h[2][16][136];

    const float br  = bih[c]       + bhh[c];
    const float bz  = bih[128 + c] + bhh[128 + c];
    const float bnx = bih[256 + c];
    const float bnh = bhh[256 + c];

    s16x8 bh[3][4];
    s16x8 bx[3][8];
#pragma unroll
    for (int p = 0; p < 3; ++p) {
        const int nrow = p * 128 + c;
#pragma unroll
        for (int kk = 0; kk < 4; ++kk) {
            const float* src = &whh[(size_t)nrow * 128 + kk * 32 + quad * 8];
            s16x8 f;
#pragma unroll
            for (int j = 0; j < 8; ++j) f[j] = (short)f2bf(src[j]);
            bh[p][kk] = f;
        }
#pragma unroll
        for (int kk = 0; kk < 8; ++kk) {
            const float* src = &wih[(size_t)nrow * 256 + kk * 32 + quad * 8];
            s16x8 f;
#pragma unroll
            for (int j = 0; j < 8; ++j) f[j] = (short)f2bf(src[j]);
            bx[p][kk] = f;
        }
    }

    auto loadP = [&](s16x8 (&P)[8], int t) {
        const unsigned short* pb = y0 + ((size_t)t * Bb + b0 + lcol) * 256 + quad * 8;
#pragma unroll
        for (int kk = 0; kk < 8; ++kk) P[kk] = *(const s16x8*)(pb + kk * 32);
    };
    s16x8 P0[8], P1[8];
    loadP(P0, dir ? 511 : 0);
    loadP(P1, dir ? 510 : 1);

    f32x4 accr = {br, br, br, br};
    f32x4 accz = {bz, bz, bz, bz};
    f32x4 accnx = {bnx, bnx, bnx, bnx};
#pragma unroll
    for (int kk = 0; kk < 8; ++kk) {
        accr  = MF(P0[kk], bx[0][kk], accr);
        accz  = MF(P0[kk], bx[1][kk], accz);
        accnx = MF(P0[kk], bx[2][kk], accnx);
    }
    loadP(P0, dir ? 509 : 2);

    float hreg[4] = {0.f, 0.f, 0.f, 0.f};
    for (int idx = tid; idx < 2 * 16 * 136; idx += THREADS)
        ((unsigned short*)lds_h)[idx] = 0;
    __syncthreads();

#define L1_STEP(S, PAR, PN)                                                    \
    do {                                                                       \
        const s16x8 a0 = *(const s16x8*)&lds_h[PAR][lcol][0  + quad * 8];      \
        const s16x8 a1 = *(const s16x8*)&lds_h[PAR][lcol][32 + quad * 8];      \
        const s16x8 a2 = *(const s16x8*)&lds_h[PAR][lcol][64 + quad * 8];      \
        const s16x8 a3 = *(const s16x8*)&lds_h[PAR][lcol][96 + quad * 8];      \
        f32x4 acchn = {bnh, bnh, bnh, bnh};                                    \
        accr = MF(a0, bh[0][0], accr); accz = MF(a0, bh[1][0], accz);          \
        acchn = MF(a0, bh[2][0], acchn);                                       \
        accr = MF(a1, bh[0][1], accr); accz = MF(a1, bh[1][1], accz);          \
        acchn = MF(a1, bh[2][1], acchn);                                       \
        accr = MF(a2, bh[0][2], accr); accz = MF(a2, bh[1][2], accz);          \
        acchn = MF(a2, bh[2][2], acchn);                                       \
        accr = MF(a3, bh[0][3], accr); accz = MF(a3, bh[1][3], accz);          \
        acchn = MF(a3, bh[2][3], acchn);                                       \
        _Pragma("unroll")                                                      \
        for (int i = 0; i < 4; ++i) {                                          \
            const float r = fsig(accr[i]);                                     \
            const float z = fsig(accz[i]);                                     \
            const float n = ftanh(accnx[i] + r * acchn[i]);                    \
            hreg[i] = (1.0f - z) * n + z * hreg[i];                            \
            lds_h[PAR ^ 1][4 * quad + i][c] = f2bf(hreg[i]);                   \
        }                                                                      \
        if ((S) < 511) {                                                       \
            accr = {br, br, br, br}; accz = {bz, bz, bz, bz};                  \
            accnx = {bnx, bnx, bnx, bnx};                                      \
            _Pragma("unroll")                                                  \
            for (int kk = 0; kk < 8; ++kk) {                                   \
                accr  = MF(PN[kk], bx[0][kk], accr);                           \
                accz  = MF(PN[kk], bx[1][kk], accz);                           \
                accnx = MF(PN[kk], bx[2][kk], accnx);                          \
            }                                                                  \
            int sp = (S) + 3; if (sp > 511) sp = 511;                          \
            loadP(PN, dir ? (511 - sp) : sp);                                  \
        } else {                                                               \
            _Pragma("unroll")                                                  \
            for (int i = 0; i < 4; ++i)                                        \
                finals[(size_t)(b0 + 4 * quad + i) * 256 + dir * 128 + c] =    \
                    hreg[i];                                                   \
        }                                                                      \
        WG_BARRIER();                                                          \
    } while (0)

    for (int s = 0; s < Tt; s += 2) {
        L1_STEP(s,     0, P1);
        L1_STEP(s + 1, 1, P0);
    }
#undef L1_STEP
}

// ---------------------------------------------------------------------------
// Layer 0 scan (R10 + dual MFMA chains): BC=4, bias-only init, shfl
// redistribution, own-row x-projection after redistribution.
// ---------------------------------------------------------------------------
__global__ __launch_bounds__(THREADS, 1) void gru_l0(
    const float* __restrict__ x,
    const float* __restrict__ wih_f, const float* __restrict__ whh_f,
    const float* __restrict__ bih_f, const float* __restrict__ bhh_f,
    const float* __restrict__ wih_b, const float* __restrict__ whh_b,
    const float* __restrict__ bih_b, const float* __restrict__ bhh_b,
    unsigned short* __restrict__ y0)
{
    const int tid  = threadIdx.x;
    const int wave = tid >> 6;
    const int lane = tid & 63;
    const int lcol = lane & 15;
    const int quad = lane >> 4;
    const int dir   = blockIdx.x >> 7;
    const int chunk = blockIdx.x & 127;
    const int b0    = chunk * 4;
    const int c     = 16 * wave + lcol;

    const float* wih = dir ? wih_b : wih_f;
    const float* whh = dir ? whh_b : whh_f;
    const float* bih = dir ? bih_b : bih_f;
    const float* bhh = dir ? bhh_b : bhh_f;

    __shared__ __align__(16) unsigned short lds_h[2][16][136];

    const float brs  = bih[c]       + bhh[c];
    const float bzs  = bih[128 + c] + bhh[128 + c];
    const float bnxs = bih[256 + c];
    const float bnh  = bhh[256 + c];

    float wr[4], wz[4], wn[4];
#pragma unroll
    for (int f = 0; f < 4; ++f) {
        wr[f] = wih[(c)       * 4 + f];
        wz[f] = wih[(128 + c) * 4 + f];
        wn[f] = wih[(256 + c) * 4 + f];
    }

    s16x8 bh[3][4];
#pragma unroll
    for (int p = 0; p < 3; ++p) {
        const int nrow = p * 128 + c;
#pragma unroll
        for (int kk = 0; kk < 4; ++kk) {
            const float* src = &whh[(size_t)nrow * 128 + kk * 32 + quad * 8];
            s16x8 f;
#pragma unroll
            for (int j = 0; j < 8; ++j) f[j] = (short)f2bf(src[j]);
            bh[p][kk] = f;
        }
    }

    auto loadX = [&](float4& X, int t) {
        X = *(const float4*)&x[((size_t)(b0 + quad) * Tt + t) * 4];
    };
    float4 X0, X1;
    loadX(X0, dir ? 511 : 0);
    loadX(X1, dir ? 510 : 1);

    float hmine = 0.f;   // this lane's h element: (row=quad, col=c)
    for (int idx = tid; idx < 2 * 16 * 136; idx += THREADS)
        ((unsigned short*)lds_h)[idx] = 0;
    __syncthreads();

    const int orow = tid >> 7;        // y0 store: row 0..3
    const int ocol = tid & 127;       // col 0..127

#define L0_STEP(S, PAR, XC)                                                    \
    do {                                                                       \
        const int t = dir ? (511 - (S)) : (S);                                 \
        const s16x8 a0 = *(const s16x8*)&lds_h[PAR][lcol][0  + quad * 8];      \
        const s16x8 a1 = *(const s16x8*)&lds_h[PAR][lcol][32 + quad * 8];      \
        const s16x8 a2 = *(const s16x8*)&lds_h[PAR][lcol][64 + quad * 8];      \
        const s16x8 a3 = *(const s16x8*)&lds_h[PAR][lcol][96 + quad * 8];      \
        /* dual chains per gate: A = a0->a2, B = a1->a3 (dep depth 2) */       \
        f32x4 rA = {brs, brs, brs, brs}, rB = {0.f, 0.f, 0.f, 0.f};            \
        f32x4 zA = {bzs, bzs, bzs, bzs}, zB = {0.f, 0.f, 0.f, 0.f};            \
        f32x4 nA = {bnh, bnh, bnh, bnh}, nB = {0.f, 0.f, 0.f, 0.f};            \
        rA = MF(a0, bh[0][0], rA); zA = MF(a0, bh[1][0], zA);                  \
        nA = MF(a0, bh[2][0], nA);                                             \
        rB = MF(a1, bh[0][1], rB); zB = MF(a1, bh[1][1], zB);                  \
        nB = MF(a1, bh[2][1], nB);                                             \
        rA = MF(a2, bh[0][2], rA); zA = MF(a2, bh[1][2], zA);                  \
        nA = MF(a2, bh[2][2], nA);                                             \
        rB = MF(a3, bh[0][3], rB); zB = MF(a3, bh[1][3], zB);                  \
        nB = MF(a3, bh[2][3], nB);                                             \
        const f32x4 accr  = rA + rB;                                           \
        const f32x4 accz  = zA + zB;                                           \
        const f32x4 acchn = nA + nB;                                           \
        const float xr = XC.x * wr[0] + XC.y * wr[1]                           \
                       + XC.z * wr[2] + XC.w * wr[3];                          \
        const float xz = XC.x * wz[0] + XC.y * wz[1]                           \
                       + XC.z * wz[2] + XC.w * wz[3];                          \
        const float xn = bnxs + XC.x * wn[0] + XC.y * wn[1]                    \
                       + XC.z * wn[2] + XC.w * wn[3];                          \
        float rr0 = __shfl(accr[0], lcol), rr1 = __shfl(accr[1], lcol);        \
        float rr2 = __shfl(accr[2], lcol), rr3 = __shfl(accr[3], lcol);        \
        float zz0 = __shfl(accz[0], lcol), zz1 = __shfl(accz[1], lcol);        \
        float zz2 = __shfl(accz[2], lcol), zz3 = __shfl(accz[3], lcol);        \
        float hh0 = __shfl(acchn[0], lcol), hh1 = __shfl(acchn[1], lcol);      \
        float hh2 = __shfl(acchn[2], lcol), hh3 = __shfl(acchn[3], lcol);      \
        const float pr = quad == 0 ? rr0 : quad == 1 ? rr1 : quad == 2 ? rr2 : rr3; \
        const float pz = quad == 0 ? zz0 : quad == 1 ? zz1 : quad == 2 ? zz2 : zz3; \
        const float ph = quad == 0 ? hh0 : quad == 1 ? hh1 : quad == 2 ? hh2 : hh3; \
        {                                                                      \
            const float r = fsig(pr + xr);                                     \
            const float z = fsig(pz + xz);                                     \
            const float n = ftanh(xn + r * ph);                                \
            hmine = (1.0f - z) * n + z * hmine;                                \
            lds_h[PAR ^ 1][quad][c] = f2bf(hmine);                             \
        }                                                                      \
        if ((S) < 510) {                                                       \
            loadX(XC, dir ? (511 - ((S) + 2)) : ((S) + 2));                    \
        }                                                                      \
        WG_BARRIER();                                                          \
        {                                                                      \
            y0[((size_t)t * Bb + b0 + orow) * 256 + dir * 128 + ocol] =        \
                lds_h[PAR ^ 1][orow][ocol];                                    \
        }                                                                      \
    } while (0)

    for (int s = 0; s < Tt; s += 2) {
        L0_STEP(s,     0, X0);
        L0_STEP(s + 1, 1, X1);
    }
#undef L0_STEP
}

// ---------------------------------------------------------------------------
// FC head: out = relu(finals @ fc1^T + b1) @ fc2^T + b2   [512,256]->[512,2]
// ---------------------------------------------------------------------------
__global__ __launch_bounds__(128) void fc_head(
    const float* __restrict__ finals,
    const float* __restrict__ fc1w, const float* __restrict__ fc1b,
    const float* __restrict__ fc2w, const float* __restrict__ fc2b,
    float* __restrict__ out)
{
    __shared__ float s_in[256];
    __shared__ float s_h1[128];
    const int b = blockIdx.x, tid = threadIdx.x;
    s_in[tid]       = finals[(size_t)b * 256 + tid];
    s_in[tid + 128] = finals[(size_t)b * 256 + 128 + tid];
    __syncthreads();
    float acc = fc1b[tid];
    const float* wrow = &fc1w[tid * 256];
#pragma unroll 8
    for (int i = 0; i < 256; ++i) acc += s_in[i] * wrow[i];
    s_h1[tid] = fmaxf(acc, 0.0f);
    __syncthreads();
    if (tid < 2) {
        float a = fc2b[tid];
        const float* w2 = &fc2w[tid * 128];
#pragma unroll 8
        for (int i = 0; i < 128; ++i) a += s_h1[i] * w2[i];
        out[b * 2 + tid] = a;
    }
}

extern "C" void kernel_launch(void* const* d_in, const int* in_sizes, int n_in,
                              void* d_out, int out_size, void* d_ws, size_t ws_size,
                              hipStream_t stream) {
    const float* x      = (const float*)d_in[0];
    const float* wih0f  = (const float*)d_in[1];
    const float* whh0f  = (const float*)d_in[2];
    const float* bih0f  = (const float*)d_in[3];
    const float* bhh0f  = (const float*)d_in[4];
    const float* wih0b  = (const float*)d_in[5];
    const float* whh0b  = (const float*)d_in[6];
    const float* bih0b  = (const float*)d_in[7];
    const float* bhh0b  = (const float*)d_in[8];
    const float* wih1f  = (const float*)d_in[9];
    const float* whh1f  = (const float*)d_in[10];
    const float* bih1f  = (const float*)d_in[11];
    const float* bhh1f  = (const float*)d_in[12];
    const float* wih1b  = (const float*)d_in[13];
    const float* whh1b  = (const float*)d_in[14];
    const float* bih1b  = (const float*)d_in[15];
    const float* bhh1b  = (const float*)d_in[16];
    const float* fc1w   = (const float*)d_in[17];
    const float* fc1b   = (const float*)d_in[18];
    const float* fc2w   = (const float*)d_in[19];
    const float* fc2b   = (const float*)d_in[20];

    const size_t Y0SZ = 134217728ull;   // y0 bf16 [512][512][256]
    const size_t HSSZ = 524288ull;      // hstate/finals f32 [512][256]
    const size_t WCSZ = 393216ull;      // wcat bf16 [768][256]
    const size_t BCSZ = 3072ull;        // bcat f32 [768]
    const size_t GX_PER_SL = 786432ull; // per sl: 2 dirs * 512 * 384 bf16 * 2B
    const size_t BASE = Y0SZ + HSSZ + WCSZ + BCSZ;

    unsigned short* y0 = (unsigned short*)d_ws;
    float*  hstate = (float*)((char*)d_ws + Y0SZ);
    unsigned short* wcat = (unsigned short*)((char*)d_ws + Y0SZ + HSSZ);
    float*  bcat   = (float*)((char*)d_ws + Y0SZ + HSSZ + WCSZ);
    unsigned short* gx0 = (unsigned short*)((char*)d_ws + BASE);
    float* out = (float*)d_out;

    const int cts[6] = {128, 64, 32, 16, 8, 4};
    int CT = 0, fused = 0;
    for (int i = 0; i < 6; ++i)
        if (BASE + 2ull * cts[i] * GX_PER_SL <= ws_size) { CT = cts[i]; fused = 1; break; }
    if (!CT)
        for (int i = 0; i < 6; ++i)
            if (BASE + (size_t)cts[i] * GX_PER_SL <= ws_size) { CT = cts[i]; break; }

    if (CT > 0) {
        unsigned short* gxb[2];
        gxb[0] = gx0;
        gxb[1] = fused ? (unsigned short*)((char*)gx0 + (size_t)CT * GX_PER_SL) : gx0;

        w_prep<<<dim3(768), dim3(256), 0, stream>>>(wih1f, wih1b, bih1f, bih1b, wcat, bcat);
        gru_l0<<<dim3(256), dim3(THREADS), 0, stream>>>(
            x, wih0f, whh0f, bih0f, bhh0f, wih0b, whh0b, bih0b, bhh0b, y0);
        const int n = Tt / CT;
        if (fused) {
            // prologue: gemm chunk 0 -> buf0
            l1_step<<<dim3(24 * CT), dim3(THREADS), 0, stream>>>(
                y0, wcat, bcat, gxb[0], gxb[0],
                whh1f, bhh1f, whh1b, bhh1b, hstate, CT, 0, 0, 1);
            for (int k = 0; k < n; ++k) {
                const int ng = (k + 1 < n) ? 24 * CT : 0;
                l1_step<<<dim3(64 + ng), dim3(THREADS), 0, stream>>>(
                    y0, wcat, bcat, gxb[k & 1], gxb[(k + 1) & 1],
                    whh1f, bhh1f, whh1b, bhh1b, hstate, CT, k + 1, 64, (k == 0) ? 1 : 0);
            }
        } else {
            for (int k = 0; k < n; ++k) {
                l1_step<<<dim3(24 * CT), dim3(THREADS), 0, stream>>>(
                    y0, wcat, bcat, gxb[0], gxb[0],
                    whh1f, bhh1f, whh1b, bhh1b, hstate, CT, k, 0, 1);
                l1_step<<<dim3(64), dim3(THREADS), 0, stream>>>(
                    y0, wcat, bcat, gxb[0], gxb[0],
                    whh1f, bhh1f, whh1b, bhh1b, hstate, CT, 0, 64, (k == 0) ? 1 : 0);
            }
        }
        fc_head<<<dim3(Bb), dim3(128), 0, stream>>>(hstate, fc1w, fc1b, fc2w, fc2b, out);
    } else {
        float* finals = (float*)((char*)d_ws + Y0SZ);
        gru_l0<<<dim3(256), dim3(THREADS), 0, stream>>>(
            x, wih0f, whh0f, bih0f, bhh0f, wih0b, whh0b, bih0b, bhh0b, y0);
        gru_l1<<<dim3(64), dim3(THREADS), 0, stream>>>(
            y0, wih1f, whh1f, bih1f, bhh1f, wih1b, whh1b, bih1b, bhh1b, finals);
        fc_head<<<dim3(Bb), dim3(128), 0, stream>>>(finals, fc1w, fc1b, fc2w, fc2b, out);
    }
}

// Round 13
// 1105.262 us; speedup vs baseline: 1.0965x; 1.0394x over previous
//
#include <hip/hip_runtime.h>
#include <stdint.h>

// GRUClassifier: 2-layer bidir GRU (H=128, T=512, B=512) + FC head.
// R13 = exact R10 restore (best measured: 1099.6 us).
//  - gru_l0: BC=4, bias-only MFMA init, shfl redistribution, own-row x-proj
//    (single 4-deep MFMA chain: R12's dual-chain variant regressed +46 us).
//  - l1: fused scan(BC=16, 64 blocks) + next-chunk gemm, ping-pong gx
//    (R11's BC=4 scan regressed via scan/gemm CU contention; R12's LDS
//    padding for CU exclusivity was neutral-to-harmful).

#define Tt 512
#define Bb 512
#define THREADS 512

using s16x8 = __attribute__((ext_vector_type(8))) short;  // 8 bf16 (4 VGPRs)
using f32x4 = __attribute__((ext_vector_type(4))) float;

#define MF(a, b, c) __builtin_amdgcn_mfma_f32_16x16x32_bf16((a), (b), (c), 0, 0, 0)

__device__ __forceinline__ unsigned short f2bf(float f) {
    union { float f; unsigned int u; } v; v.f = f;
    unsigned int u = v.u;
    u += 0x7fffu + ((u >> 16) & 1u);   // RNE
    return (unsigned short)(u >> 16);
}
__device__ __forceinline__ float bf2f(unsigned short h) {
    union { unsigned int u; float f; } v; v.u = ((unsigned int)h) << 16;
    return v.f;
}

__device__ __forceinline__ float fsig(float x) {
    return __builtin_amdgcn_rcpf(1.0f + __expf(-x));
}
__device__ __forceinline__ float ftanh(float x) {
    return 2.0f * __builtin_amdgcn_rcpf(1.0f + __expf(-2.0f * x)) - 1.0f;
}

// Raw workgroup barrier: drains LDS ops only; in-flight global register
// prefetch loads survive it (vmcnt not drained).
#define WG_BARRIER() asm volatile("s_waitcnt lgkmcnt(0)\n\ts_barrier" ::: "memory")

// ---------------------------------------------------------------------------
// w_prep: pack W_ih1 (both dirs) to bf16 [768][256] + bias concat [768].
// ---------------------------------------------------------------------------
__global__ void w_prep(const float* __restrict__ wihf, const float* __restrict__ wihb,
                       const float* __restrict__ bihf, const float* __restrict__ bihb,
                       unsigned short* __restrict__ wcat, float* __restrict__ bcat)
{
    const int n = blockIdx.x;   // 0..767
    const int k = threadIdx.x;  // 0..255
    const float* src = (n < 384) ? &wihf[(size_t)n * 256] : &wihb[(size_t)(n - 384) * 256];
    wcat[(size_t)n * 256 + k] = f2bf(src[k]);
    if (k == 0) bcat[n] = (n < 384) ? bihf[n] : bihb[n - 384];
}

// ---------------------------------------------------------------------------
// l1_step: fused chunk kernel.
//   blocks [0,nscan): scan role (BC=16), reads gx_rd.
//   blocks [nscan,..): gemm role, chunk kgemm, writes gx_wr.
//   gx layout [(dir*CT+sl)*512 + b]*384 + gc  (gc = gate*128 + col).
// ---------------------------------------------------------------------------
__global__ __launch_bounds__(THREADS) void l1_step(
    const unsigned short* __restrict__ y0,
    const unsigned short* __restrict__ wcat,
    const float* __restrict__ bcat,
    const unsigned short* __restrict__ gx_rd,
    unsigned short* __restrict__ gx_wr,
    const float* __restrict__ whh_f, const float* __restrict__ bhh_f,
    const float* __restrict__ whh_b, const float* __restrict__ bhh_b,
    float* __restrict__ hstate,
    int CT, int kgemm, int nscan, int first)
{
    const int bid  = blockIdx.x;
    const int tid  = threadIdx.x;
    const int wave = tid >> 6;
    const int lane = tid & 63;
    const int lcol = lane & 15;
    const int quad = lane >> 4;

    __shared__ __align__(16) unsigned short lA[128][136];
    __shared__ __align__(16) unsigned short lB[128][136];
    __shared__ __align__(16) unsigned short lds_h[2][16][136];

    if (bid >= nscan) {
        // =============================== GEMM role ===========================
        int gb = bid - nscan;
        const int nt = gb % 3;  gb /= 3;
        const int bt = gb & 3;  gb >>= 2;
        const int sl = gb % CT;
        const int dir = gb / CT;
        const int s  = kgemm * CT + sl;
        const int t  = dir ? (511 - s) : s;
        const int bb = bt << 7;

        const unsigned short* Abase = y0 + ((size_t)t * 512 + bb) * 256;
        const unsigned short* Bbase = wcat + ((size_t)dir * 384 + nt * 128) * 256;

        const int r0 = (wave >> 2) * 64;   // 0 or 64
        const int c0 = (wave & 3) * 32;    // 0,32,64,96

        f32x4 acc[4][2];
#pragma unroll
        for (int ti = 0; ti < 4; ++ti)
#pragma unroll
            for (int tj = 0; tj < 2; ++tj) acc[ti][tj] = {0.f, 0.f, 0.f, 0.f};

        const int rstg = tid >> 4;         // 0..31
        const int cstg = (tid & 15) * 8;   // 0..120 (<136)

#pragma unroll
        for (int kh = 0; kh < 2; ++kh) {
            if (kh) __syncthreads();
#pragma unroll
            for (int it = 0; it < 4; ++it) {
                const int r = it * 32 + rstg;
                *(ulonglong2*)&lA[r][cstg] =
                    *(const ulonglong2*)&Abase[(size_t)r * 256 + kh * 128 + cstg];
                *(ulonglong2*)&lB[r][cstg] =
                    *(const ulonglong2*)&Bbase[(size_t)r * 256 + kh * 128 + cstg];
            }
            __syncthreads();

#pragma unroll
            for (int kk = 0; kk < 4; ++kk) {
                s16x8 af[4], bfv[2];
#pragma unroll
                for (int ti = 0; ti < 4; ++ti)
                    af[ti] = *(const s16x8*)&lA[r0 + ti * 16 + lcol][kk * 32 + quad * 8];
#pragma unroll
                for (int tj = 0; tj < 2; ++tj)
                    bfv[tj] = *(const s16x8*)&lB[c0 + tj * 16 + lcol][kk * 32 + quad * 8];
#pragma unroll
                for (int ti = 0; ti < 4; ++ti)
#pragma unroll
                    for (int tj = 0; tj < 2; ++tj)
                        acc[ti][tj] = MF(af[ti], bfv[tj], acc[ti][tj]);
            }
        }

        float bias[2];
#pragma unroll
        for (int tj = 0; tj < 2; ++tj)
            bias[tj] = bcat[dir * 384 + nt * 128 + c0 + tj * 16 + lcol];

        __syncthreads();   // fragment reads done; reuse lA as C staging

        unsigned short* lC = &lA[0][0];
#pragma unroll
        for (int ti = 0; ti < 4; ++ti)
#pragma unroll
            for (int tj = 0; tj < 2; ++tj) {
                const int col = c0 + tj * 16 + lcol;
#pragma unroll
                for (int i = 0; i < 4; ++i)
                    lC[(size_t)(r0 + ti * 16 + 4 * quad + i) * 136 + col] =
                        f2bf(acc[ti][tj][i] + bias[tj]);
            }
        __syncthreads();

        unsigned short* ob = gx_wr + ((size_t)(dir * CT + sl) * 512 + bb) * 384 + nt * 128;
#pragma unroll
        for (int it = 0; it < 4; ++it) {
            const int r = it * 32 + rstg;
            *(ulonglong2*)&ob[(size_t)r * 384 + cstg] =
                *(const ulonglong2*)&lC[(size_t)r * 136 + cstg];
        }
        return;
    }

    // ============================ SCAN role (BC=16) ==========================
    const int dir   = bid >> 5;
    const int chunk = bid & 31;
    const int b0    = chunk * 16;
    const int c     = 16 * wave + lcol;

    const float* whh = dir ? whh_b : whh_f;
    const float* bhh = dir ? bhh_b : bhh_f;

    const float bhr = bhh[c];
    const float bhz = bhh[128 + c];
    const float bhn = bhh[256 + c];

    s16x8 bh[3][4];
#pragma unroll
    for (int p = 0; p < 3; ++p) {
        const int nrow = p * 128 + c;
#pragma unroll
        for (int kk = 0; kk < 4; ++kk) {
            const float* src = &whh[(size_t)nrow * 128 + kk * 32 + quad * 8];
            s16x8 f;
#pragma unroll
            for (int j = 0; j < 8; ++j) f[j] = (short)f2bf(src[j]);
            bh[p][kk] = f;
        }
    }

    const unsigned short* gbase = gx_rd + (size_t)dir * CT * 512 * 384;
    auto loadGX = [&](unsigned short (&G)[12], int sl) {
        const unsigned short* gp = gbase + ((size_t)sl * 512 + b0 + 4 * quad) * 384;
#pragma unroll
        for (int g = 0; g < 3; ++g)
#pragma unroll
            for (int i = 0; i < 4; ++i)
                G[g * 4 + i] = gp[(size_t)i * 384 + g * 128 + c];
    };
    unsigned short G0[12], G1[12];
    loadGX(G0, 0);
    loadGX(G1, 1);

    float hreg[4];
    const int gb2 = tid >> 5;          // 0..15 batch row for LDS init
    const int j0  = (tid & 31) * 4;    // 0..124
    if (first) {
#pragma unroll
        for (int i = 0; i < 4; ++i) hreg[i] = 0.f;
        ushort4 z4; z4.x = 0; z4.y = 0; z4.z = 0; z4.w = 0;
        *(ushort4*)&lds_h[0][gb2][j0] = z4;
    } else {
#pragma unroll
        for (int i = 0; i < 4; ++i)
            hreg[i] = hstate[(size_t)(b0 + 4 * quad + i) * 256 + dir * 128 + c];
        ushort4 hv;
        hv.x = f2bf(hstate[(size_t)(b0 + gb2) * 256 + dir * 128 + j0 + 0]);
        hv.y = f2bf(hstate[(size_t)(b0 + gb2) * 256 + dir * 128 + j0 + 1]);
        hv.z = f2bf(hstate[(size_t)(b0 + gb2) * 256 + dir * 128 + j0 + 2]);
        hv.w = f2bf(hstate[(size_t)(b0 + gb2) * 256 + dir * 128 + j0 + 3]);
        *(ushort4*)&lds_h[0][gb2][j0] = hv;
    }
    __syncthreads();

#define L1C_STEP(S, PAR, G)                                                    \
    do {                                                                       \
        const s16x8 a0 = *(const s16x8*)&lds_h[PAR][lcol][0  + quad * 8];      \
        const s16x8 a1 = *(const s16x8*)&lds_h[PAR][lcol][32 + quad * 8];      \
        const s16x8 a2 = *(const s16x8*)&lds_h[PAR][lcol][64 + quad * 8];      \
        const s16x8 a3 = *(const s16x8*)&lds_h[PAR][lcol][96 + quad * 8];      \
        f32x4 rA = {bhr, bhr, bhr, bhr}, rB = {0.f, 0.f, 0.f, 0.f};            \
        f32x4 zA = {bhz, bhz, bhz, bhz}, zB = {0.f, 0.f, 0.f, 0.f};            \
        f32x4 nA = {bhn, bhn, bhn, bhn}, nB = {0.f, 0.f, 0.f, 0.f};            \
        rA = MF(a0, bh[0][0], rA); zA = MF(a0, bh[1][0], zA);                  \
        nA = MF(a0, bh[2][0], nA);                                             \
        rB = MF(a1, bh[0][1], rB); zB = MF(a1, bh[1][1], zB);                  \
        nB = MF(a1, bh[2][1], nB);                                             \
        rA = MF(a2, bh[0][2], rA); zA = MF(a2, bh[1][2], zA);                  \
        nA = MF(a2, bh[2][2], nA);                                             \
        rB = MF(a3, bh[0][3], rB); zB = MF(a3, bh[1][3], zB);                  \
        nB = MF(a3, bh[2][3], nB);                                             \
        _Pragma("unroll")                                                      \
        for (int i = 0; i < 4; ++i) {                                          \
            const float r = fsig(rA[i] + rB[i] + bf2f(G[i]));                  \
            const float z = fsig(zA[i] + zB[i] + bf2f(G[4 + i]));              \
            const float n = ftanh(bf2f(G[8 + i]) + r * (nA[i] + nB[i]));       \
            hreg[i] = (1.0f - z) * n + z * hreg[i];                            \
            lds_h[PAR ^ 1][4 * quad + i][c] = f2bf(hreg[i]);                   \
        }                                                                      \
        if ((S) < CT - 2) {                                                    \
            loadGX(G, (S) + 2);                                                \
        } else if ((S) == CT - 1) {                                            \
            _Pragma("unroll")                                                  \
            for (int i = 0; i < 4; ++i)                                        \
                hstate[(size_t)(b0 + 4 * quad + i) * 256 + dir * 128 + c] =    \
                    hreg[i];                                                   \
        }                                                                      \
        WG_BARRIER();                                                          \
    } while (0)

    for (int sl = 0; sl < CT; sl += 2) {
        L1C_STEP(sl,     0, G0);
        L1C_STEP(sl + 1, 1, G1);
    }
#undef L1C_STEP
}

// ---------------------------------------------------------------------------
// Fallback layer-1 (fused Gx, verbatim from passing R3) — if no CT fits.
// ---------------------------------------------------------------------------
__global__ __launch_bounds__(THREADS, 1) void gru_l1(
    const unsigned short* __restrict__ y0,
    const float* __restrict__ wih_f, const float* __restrict__ whh_f,
    const float* __restrict__ bih_f, const float* __restrict__ bhh_f,
    const float* __restrict__ wih_b, const float* __restrict__ whh_b,
    const float* __restrict__ bih_b, const float* __restrict__ bhh_b,
    float* __restrict__ finals)
{
    const int tid  = threadIdx.x;
    const int wave = tid >> 6;
    const int lane = tid & 63;
    const int lcol = lane & 15;
    const int quad = lane >> 4;
    const int dir   = blockIdx.x >> 5;
    const int b0    = (blockIdx.x & 31) * 16;
    const int c     = 16 * wave + lcol;

    const float* wih = dir ? wih_b : wih_f;
    const float* whh = dir ? whh_b : whh_f;
    const float* bih = dir ? bih_b : bih_f;
    const float* bhh = dir ? bhh_b : bhh_f;

    __shared__ __align__(16) unsigned short lds_h[2][16][136];

    const float br  = bih[c]       + bhh[c];
    const float bz  = bih[128 + c] + bhh[128 + c];
    const float bnx = bih[256 + c];
    const float bnh = bhh[256 + c];

    s16x8 bh[3][4];
    s16x8 bx[3][8];
#pragma unroll
    for (int p = 0; p < 3; ++p) {
        const int nrow = p * 128 + c;
#pragma unroll
        for (int kk = 0; kk < 4; ++kk) {
            const float* src = &whh[(size_t)nrow * 128 + kk * 32 + quad * 8];
            s16x8 f;
#pragma unroll
            for (int j = 0; j < 8; ++j) f[j] = (short)f2bf(src[j]);
            bh[p][kk] = f;
        }
#pragma unroll
        for (int kk = 0; kk < 8; ++kk) {
            const float* src = &wih[(size_t)nrow * 256 + kk * 32 + quad * 8];
            s16x8 f;
#pragma unroll
            for (int j = 0; j < 8; ++j) f[j] = (short)f2bf(src[j]);
            bx[p][kk] = f;
        }
    }

    auto loadP = [&](s16x8 (&P)[8], int t) {
        const unsigned short* pb = y0 + ((size_t)t * Bb + b0 + lcol) * 256 + quad * 8;
#pragma unroll
        for (int kk = 0; kk < 8; ++kk) P[kk] = *(const s16x8*)(pb + kk * 32);
    };
    s16x8 P0[8], P1[8];
    loadP(P0, dir ? 511 : 0);
    loadP(P1, dir ? 510 : 1);

    f32x4 accr = {br, br, br, br};
    f32x4 accz = {bz, bz, bz, bz};
    f32x4 accnx = {bnx, bnx, bnx, bnx};
#pragma unroll
    for (int kk = 0; kk < 8; ++kk) {
        accr  = MF(P0[kk], bx[0][kk], accr);
        accz  = MF(P0[kk], bx[1][kk], accz);
        accnx = MF(P0[kk], bx[2][kk], accnx);
    }
    loadP(P0, dir ? 509 : 2);

    float hreg[4] = {0.f, 0.f, 0.f, 0.f};
    for (int idx = tid; idx < 2 * 16 * 136; idx += THREADS)
        ((unsigned short*)lds_h)[idx] = 0;
    __syncthreads();

#define L1_STEP(S, PAR, PN)                                                    \
    do {                                                                       \
        const s16x8 a0 = *(const s16x8*)&lds_h[PAR][lcol][0  + quad * 8];      \
        const s16x8 a1 = *(const s16x8*)&lds_h[PAR][lcol][32 + quad * 8];      \
        const s16x8 a2 = *(const s16x8*)&lds_h[PAR][lcol][64 + quad * 8];      \
        const s16x8 a3 = *(const s16x8*)&lds_h[PAR][lcol][96 + quad * 8];      \
        f32x4 acchn = {bnh, bnh, bnh, bnh};                                    \
        accr = MF(a0, bh[0][0], accr); accz = MF(a0, bh[1][0], accz);          \
        acchn = MF(a0, bh[2][0], acchn);                                       \
        accr = MF(a1, bh[0][1], accr); accz = MF(a1, bh[1][1], accz);          \
        acchn = MF(a1, bh[2][1], acchn);                                       \
        accr = MF(a2, bh[0][2], accr); accz = MF(a2, bh[1][2], accz);          \
        acchn = MF(a2, bh[2][2], acchn);                                       \
        accr = MF(a3, bh[0][3], accr); accz = MF(a3, bh[1][3], accz);          \
        acchn = MF(a3, bh[2][3], acchn);                                       \
        _Pragma("unroll")                                                      \
        for (int i = 0; i < 4; ++i) {                                          \
            const float r = fsig(accr[i]);                                     \
            const float z = fsig(accz[i]);                                     \
            const float n = ftanh(accnx[i] + r * acchn[i]);                    \
            hreg[i] = (1.0f - z) * n + z * hreg[i];                            \
            lds_h[PAR ^ 1][4 * quad + i][c] = f2bf(hreg[i]);                   \
        }                                                                      \
        if ((S) < 511) {                                                       \
            accr = {br, br, br, br}; accz = {bz, bz, bz, bz};                  \
            accnx = {bnx, bnx, bnx, bnx};                                      \
            _Pragma("unroll")                                                  \
            for (int kk = 0; kk < 8; ++kk) {                                   \
                accr  = MF(PN[kk], bx[0][kk], accr);                           \
                accz  = MF(PN[kk], bx[1][kk], accz);                           \
                accnx = MF(PN[kk], bx[2][kk], accnx);                          \
            }                                                                  \
            int sp = (S) + 3; if (sp > 511) sp = 511;                          \
            loadP(PN, dir ? (511 - sp) : sp);                                  \
        } else {                                                               \
            _Pragma("unroll")                                                  \
            for (int i = 0; i < 4; ++i)                                        \
                finals[(size_t)(b0 + 4 * quad + i) * 256 + dir * 128 + c] =    \
                    hreg[i];                                                   \
        }                                                                      \
        WG_BARRIER();                                                          \
    } while (0)

    for (int s = 0; s < Tt; s += 2) {
        L1_STEP(s,     0, P1);
        L1_STEP(s + 1, 1, P0);
    }
#undef L1_STEP
}

// ---------------------------------------------------------------------------
// Layer 0 scan (verbatim R10): BC=4, bias-only MFMA init, shfl redistribution,
// own-row x-projection after redistribution.
// ---------------------------------------------------------------------------
__global__ __launch_bounds__(THREADS, 1) void gru_l0(
    const float* __restrict__ x,
    const float* __restrict__ wih_f, const float* __restrict__ whh_f,
    const float* __restrict__ bih_f, const float* __restrict__ bhh_f,
    const float* __restrict__ wih_b, const float* __restrict__ whh_b,
    const float* __restrict__ bih_b, const float* __restrict__ bhh_b,
    unsigned short* __restrict__ y0)
{
    const int tid  = threadIdx.x;
    const int wave = tid >> 6;
    const int lane = tid & 63;
    const int lcol = lane & 15;
    const int quad = lane >> 4;
    const int dir   = blockIdx.x >> 7;
    const int chunk = blockIdx.x & 127;
    const int b0    = chunk * 4;
    const int c     = 16 * wave + lcol;

    const float* wih = dir ? wih_b : wih_f;
    const float* whh = dir ? whh_b : whh_f;
    const float* bih = dir ? bih_b : bih_f;
    const float* bhh = dir ? bhh_b : bhh_f;

    __shared__ __align__(16) unsigned short lds_h[2][16][136];

    const float brs  = bih[c]       + bhh[c];
    const float bzs  = bih[128 + c] + bhh[128 + c];
    const float bnxs = bih[256 + c];
    const float bnh  = bhh[256 + c];

    float wr[4], wz[4], wn[4];
#pragma unroll
    for (int f = 0; f < 4; ++f) {
        wr[f] = wih[(c)       * 4 + f];
        wz[f] = wih[(128 + c) * 4 + f];
        wn[f] = wih[(256 + c) * 4 + f];
    }

    s16x8 bh[3][4];
#pragma unroll
    for (int p = 0; p < 3; ++p) {
        const int nrow = p * 128 + c;
#pragma unroll
        for (int kk = 0; kk < 4; ++kk) {
            const float* src = &whh[(size_t)nrow * 128 + kk * 32 + quad * 8];
            s16x8 f;
#pragma unroll
            for (int j = 0; j < 8; ++j) f[j] = (short)f2bf(src[j]);
            bh[p][kk] = f;
        }
    }

    auto loadX = [&](float4& X, int t) {
        X = *(const float4*)&x[((size_t)(b0 + quad) * Tt + t) * 4];
    };
    float4 X0, X1;
    loadX(X0, dir ? 511 : 0);
    loadX(X1, dir ? 510 : 1);

    float hmine = 0.f;   // this lane's h element: (row=quad, col=c)
    for (int idx = tid; idx < 2 * 16 * 136; idx += THREADS)
        ((unsigned short*)lds_h)[idx] = 0;
    __syncthreads();

    const int orow = tid >> 7;        // y0 store: row 0..3
    const int ocol = tid & 127;       // col 0..127

#define L0_STEP(S, PAR, XC)                                                    \
    do {                                                                       \
        const int t = dir ? (511 - (S)) : (S);                                 \
        const s16x8 a0 = *(const s16x8*)&lds_h[PAR][lcol][0  + quad * 8];      \
        const s16x8 a1 = *(const s16x8*)&lds_h[PAR][lcol][32 + quad * 8];      \
        const s16x8 a2 = *(const s16x8*)&lds_h[PAR][lcol][64 + quad * 8];      \
        const s16x8 a3 = *(const s16x8*)&lds_h[PAR][lcol][96 + quad * 8];      \
        f32x4 accr  = {brs, brs, brs, brs};                                    \
        f32x4 accz  = {bzs, bzs, bzs, bzs};                                    \
        f32x4 acchn = {bnh, bnh, bnh, bnh};                                    \
        accr = MF(a0, bh[0][0], accr); accz = MF(a0, bh[1][0], accz);          \
        acchn = MF(a0, bh[2][0], acchn);                                       \
        accr = MF(a1, bh[0][1], accr); accz = MF(a1, bh[1][1], accz);          \
        acchn = MF(a1, bh[2][1], acchn);                                       \
        accr = MF(a2, bh[0][2], accr); accz = MF(a2, bh[1][2], accz);          \
        acchn = MF(a2, bh[2][2], acchn);                                       \
        accr = MF(a3, bh[0][3], accr); accz = MF(a3, bh[1][3], accz);          \
        acchn = MF(a3, bh[2][3], acchn);                                       \
        const float xr = XC.x * wr[0] + XC.y * wr[1]                           \
                       + XC.z * wr[2] + XC.w * wr[3];                          \
        const float xz = XC.x * wz[0] + XC.y * wz[1]                           \
                       + XC.z * wz[2] + XC.w * wz[3];                          \
        const float xn = bnxs + XC.x * wn[0] + XC.y * wn[1]                    \
                       + XC.z * wn[2] + XC.w * wn[3];                          \
        float rr0 = __shfl(accr[0], lcol), rr1 = __shfl(accr[1], lcol);        \
        float rr2 = __shfl(accr[2], lcol), rr3 = __shfl(accr[3], lcol);        \
        float zz0 = __shfl(accz[0], lcol), zz1 = __shfl(accz[1], lcol);        \
        float zz2 = __shfl(accz[2], lcol), zz3 = __shfl(accz[3], lcol);        \
        float hh0 = __shfl(acchn[0], lcol), hh1 = __shfl(acchn[1], lcol);      \
        float hh2 = __shfl(acchn[2], lcol), hh3 = __shfl(acchn[3], lcol);      \
        const float pr = quad == 0 ? rr0 : quad == 1 ? rr1 : quad == 2 ? rr2 : rr3; \
        const float pz = quad == 0 ? zz0 : quad == 1 ? zz1 : quad == 2 ? zz2 : zz3; \
        const float ph = quad == 0 ? hh0 : quad == 1 ? hh1 : quad == 2 ? hh2 : hh3; \
        {                                                                      \
            const float r = fsig(pr + xr);                                     \
            const float z = fsig(pz + xz);                                     \
            const float n = ftanh(xn + r * ph);                                \
            hmine = (1.0f - z) * n + z * hmine;                                \
            lds_h[PAR ^ 1][quad][c] = f2bf(hmine);                             \
        }                                                                      \
        if ((S) < 510) {                                                       \
            loadX(XC, dir ? (511 - ((S) + 2)) : ((S) + 2));                    \
        }                                                                      \
        WG_BARRIER();                                                          \
        {                                                                      \
            y0[((size_t)t * Bb + b0 + orow) * 256 + dir * 128 + ocol] =        \
                lds_h[PAR ^ 1][orow][ocol];                                    \
        }                                                                      \
    } while (0)

    for (int s = 0; s < Tt; s += 2) {
        L0_STEP(s,     0, X0);
        L0_STEP(s + 1, 1, X1);
    }
#undef L0_STEP
}

// ---------------------------------------------------------------------------
// FC head: out = relu(finals @ fc1^T + b1) @ fc2^T + b2   [512,256]->[512,2]
// ---------------------------------------------------------------------------
__global__ __launch_bounds__(128) void fc_head(
    const float* __restrict__ finals,
    const float* __restrict__ fc1w, const float* __restrict__ fc1b,
    const float* __restrict__ fc2w, const float* __restrict__ fc2b,
    float* __restrict__ out)
{
    __shared__ float s_in[256];
    __shared__ float s_h1[128];
    const int b = blockIdx.x, tid = threadIdx.x;
    s_in[tid]       = finals[(size_t)b * 256 + tid];
    s_in[tid + 128] = finals[(size_t)b * 256 + 128 + tid];
    __syncthreads();
    float acc = fc1b[tid];
    const float* wrow = &fc1w[tid * 256];
#pragma unroll 8
    for (int i = 0; i < 256; ++i) acc += s_in[i] * wrow[i];
    s_h1[tid] = fmaxf(acc, 0.0f);
    __syncthreads();
    if (tid < 2) {
        float a = fc2b[tid];
        const float* w2 = &fc2w[tid * 128];
#pragma unroll 8
        for (int i = 0; i < 128; ++i) a += s_h1[i] * w2[i];
        out[b * 2 + tid] = a;
    }
}

extern "C" void kernel_launch(void* const* d_in, const int* in_sizes, int n_in,
                              void* d_out, int out_size, void* d_ws, size_t ws_size,
                              hipStream_t stream) {
    const float* x      = (const float*)d_in[0];
    const float* wih0f  = (const float*)d_in[1];
    const float* whh0f  = (const float*)d_in[2];
    const float* bih0f  = (const float*)d_in[3];
    const float* bhh0f  = (const float*)d_in[4];
    const float* wih0b  = (const float*)d_in[5];
    const float* whh0b  = (const float*)d_in[6];
    const float* bih0b  = (const float*)d_in[7];
    const float* bhh0b  = (const float*)d_in[8];
    const float* wih1f  = (const float*)d_in[9];
    const float* whh1f  = (const float*)d_in[10];
    const float* bih1f  = (const float*)d_in[11];
    const float* bhh1f  = (const float*)d_in[12];
    const float* wih1b  = (const float*)d_in[13];
    const float* whh1b  = (const float*)d_in[14];
    const float* bih1b  = (const float*)d_in[15];
    const float* bhh1b  = (const float*)d_in[16];
    const float* fc1w   = (const float*)d_in[17];
    const float* fc1b   = (const float*)d_in[18];
    const float* fc2w   = (const float*)d_in[19];
    const float* fc2b   = (const float*)d_in[20];

    const size_t Y0SZ = 134217728ull;   // y0 bf16 [512][512][256]
    const size_t HSSZ = 524288ull;      // hstate/finals f32 [512][256]
    const size_t WCSZ = 393216ull;      // wcat bf16 [768][256]
    const size_t BCSZ = 3072ull;        // bcat f32 [768]
    const size_t GX_PER_SL = 786432ull; // per sl: 2 dirs * 512 * 384 bf16 * 2B
    const size_t BASE = Y0SZ + HSSZ + WCSZ + BCSZ;

    unsigned short* y0 = (unsigned short*)d_ws;
    float*  hstate = (float*)((char*)d_ws + Y0SZ);
    unsigned short* wcat = (unsigned short*)((char*)d_ws + Y0SZ + HSSZ);
    float*  bcat   = (float*)((char*)d_ws + Y0SZ + HSSZ + WCSZ);
    unsigned short* gx0 = (unsigned short*)((char*)d_ws + BASE);
    float* out = (float*)d_out;

    const int cts[6] = {128, 64, 32, 16, 8, 4};
    int CT = 0, fused = 0;
    for (int i = 0; i < 6; ++i)
        if (BASE + 2ull * cts[i] * GX_PER_SL <= ws_size) { CT = cts[i]; fused = 1; break; }
    if (!CT)
        for (int i = 0; i < 6; ++i)
            if (BASE + (size_t)cts[i] * GX_PER_SL <= ws_size) { CT = cts[i]; break; }

    if (CT > 0) {
        unsigned short* gxb[2];
        gxb[0] = gx0;
        gxb[1] = fused ? (unsigned short*)((char*)gx0 + (size_t)CT * GX_PER_SL) : gx0;

        w_prep<<<dim3(768), dim3(256), 0, stream>>>(wih1f, wih1b, bih1f, bih1b, wcat, bcat);
        gru_l0<<<dim3(256), dim3(THREADS), 0, stream>>>(
            x, wih0f, whh0f, bih0f, bhh0f, wih0b, whh0b, bih0b, bhh0b, y0);
        const int n = Tt / CT;
        if (fused) {
            // prologue: gemm chunk 0 -> buf0
            l1_step<<<dim3(24 * CT), dim3(THREADS), 0, stream>>>(
                y0, wcat, bcat, gxb[0], gxb[0],
                whh1f, bhh1f, whh1b, bhh1b, hstate, CT, 0, 0, 1);
            for (int k = 0; k < n; ++k) {
                const int ng = (k + 1 < n) ? 24 * CT : 0;
                l1_step<<<dim3(64 + ng), dim3(THREADS), 0, stream>>>(
                    y0, wcat, bcat, gxb[k & 1], gxb[(k + 1) & 1],
                    whh1f, bhh1f, whh1b, bhh1b, hstate, CT, k + 1, 64, (k == 0) ? 1 : 0);
            }
        } else {
            for (int k = 0; k < n; ++k) {
                l1_step<<<dim3(24 * CT), dim3(THREADS), 0, stream>>>(
                    y0, wcat, bcat, gxb[0], gxb[0],
                    whh1f, bhh1f, whh1b, bhh1b, hstate, CT, k, 0, 1);
                l1_step<<<dim3(64), dim3(THREADS), 0, stream>>>(
                    y0, wcat, bcat, gxb[0], gxb[0],
                    whh1f, bhh1f, whh1b, bhh1b, hstate, CT, 0, 64, (k == 0) ? 1 : 0);
            }
        }
        fc_head<<<dim3(Bb), dim3(128), 0, stream>>>(hstate, fc1w, fc1b, fc2w, fc2b, out);
    } else {
        float* finals = (float*)((char*)d_ws + Y0SZ);
        gru_l0<<<dim3(256), dim3(THREADS), 0, stream>>>(
            x, wih0f, whh0f, bih0f, bhh0f, wih0b, whh0b, bih0b, bhh0b, y0);
        gru_l1<<<dim3(64), dim3(THREADS), 0, stream>>>(
            y0, wih1f, whh1f, bih1f, bhh1f, wih1b, whh1b, bih1b, bhh1b, finals);
        fc_head<<<dim3(Bb), dim3(128), 0, stream>>>(finals, fc1w, fc1b, fc2w, fc2b, out);
    }
}

// Round 14
// 1004.118 us; speedup vs baseline: 1.2070x; 1.1007x over previous
//
#include <hip/hip_runtime.h>
#include <stdint.h>

// GRUClassifier: 2-layer bidir GRU (H=128, T=512, B=512) + FC head.
// R14 = R13/R10 + gru_l0 shfl elimination via A-row replication:
// a-fragment reads row (lcol&3) so A[m] = h[b0 + m%4]; MFMA output reg i
// then holds batch row i for EVERY lane -> lane selects acc[quad] directly.
// Deletes 12 ds_bpermute/step (4-way LDS conflicts, ~112 cyc/step measured:
// SQ_LDS_BANK_CONFLICT 4.19M pre-shfl -> 18.87M with shfl).
// l1 pipeline verbatim R10/R13 (fused BC=16 scan + next-chunk gemm).

#define Tt 512
#define Bb 512
#define THREADS 512

using s16x8 = __attribute__((ext_vector_type(8))) short;  // 8 bf16 (4 VGPRs)
using f32x4 = __attribute__((ext_vector_type(4))) float;

#define MF(a, b, c) __builtin_amdgcn_mfma_f32_16x16x32_bf16((a), (b), (c), 0, 0, 0)

__device__ __forceinline__ unsigned short f2bf(float f) {
    union { float f; unsigned int u; } v; v.f = f;
    unsigned int u = v.u;
    u += 0x7fffu + ((u >> 16) & 1u);   // RNE
    return (unsigned short)(u >> 16);
}
__device__ __forceinline__ float bf2f(unsigned short h) {
    union { unsigned int u; float f; } v; v.u = ((unsigned int)h) << 16;
    return v.f;
}

__device__ __forceinline__ float fsig(float x) {
    return __builtin_amdgcn_rcpf(1.0f + __expf(-x));
}
__device__ __forceinline__ float ftanh(float x) {
    return 2.0f * __builtin_amdgcn_rcpf(1.0f + __expf(-2.0f * x)) - 1.0f;
}

// Raw workgroup barrier: drains LDS ops only; in-flight global register
// prefetch loads survive it (vmcnt not drained).
#define WG_BARRIER() asm volatile("s_waitcnt lgkmcnt(0)\n\ts_barrier" ::: "memory")

// ---------------------------------------------------------------------------
// w_prep: pack W_ih1 (both dirs) to bf16 [768][256] + bias concat [768].
// ---------------------------------------------------------------------------
__global__ void w_prep(const float* __restrict__ wihf, const float* __restrict__ wihb,
                       const float* __restrict__ bihf, const float* __restrict__ bihb,
                       unsigned short* __restrict__ wcat, float* __restrict__ bcat)
{
    const int n = blockIdx.x;   // 0..767
    const int k = threadIdx.x;  // 0..255
    const float* src = (n < 384) ? &wihf[(size_t)n * 256] : &wihb[(size_t)(n - 384) * 256];
    wcat[(size_t)n * 256 + k] = f2bf(src[k]);
    if (k == 0) bcat[n] = (n < 384) ? bihf[n] : bihb[n - 384];
}

// ---------------------------------------------------------------------------
// l1_step: fused chunk kernel (verbatim R13).
//   blocks [0,nscan): scan role (BC=16), reads gx_rd.
//   blocks [nscan,..): gemm role, chunk kgemm, writes gx_wr.
//   gx layout [(dir*CT+sl)*512 + b]*384 + gc  (gc = gate*128 + col).
// ---------------------------------------------------------------------------
__global__ __launch_bounds__(THREADS) void l1_step(
    const unsigned short* __restrict__ y0,
    const unsigned short* __restrict__ wcat,
    const float* __restrict__ bcat,
    const unsigned short* __restrict__ gx_rd,
    unsigned short* __restrict__ gx_wr,
    const float* __restrict__ whh_f, const float* __restrict__ bhh_f,
    const float* __restrict__ whh_b, const float* __restrict__ bhh_b,
    float* __restrict__ hstate,
    int CT, int kgemm, int nscan, int first)
{
    const int bid  = blockIdx.x;
    const int tid  = threadIdx.x;
    const int wave = tid >> 6;
    const int lane = tid & 63;
    const int lcol = lane & 15;
    const int quad = lane >> 4;

    __shared__ __align__(16) unsigned short lA[128][136];
    __shared__ __align__(16) unsigned short lB[128][136];
    __shared__ __align__(16) unsigned short lds_h[2][16][136];

    if (bid >= nscan) {
        // =============================== GEMM role ===========================
        int gb = bid - nscan;
        const int nt = gb % 3;  gb /= 3;
        const int bt = gb & 3;  gb >>= 2;
        const int sl = gb % CT;
        const int dir = gb / CT;
        const int s  = kgemm * CT + sl;
        const int t  = dir ? (511 - s) : s;
        const int bb = bt << 7;

        const unsigned short* Abase = y0 + ((size_t)t * 512 + bb) * 256;
        const unsigned short* Bbase = wcat + ((size_t)dir * 384 + nt * 128) * 256;

        const int r0 = (wave >> 2) * 64;   // 0 or 64
        const int c0 = (wave & 3) * 32;    // 0,32,64,96

        f32x4 acc[4][2];
#pragma unroll
        for (int ti = 0; ti < 4; ++ti)
#pragma unroll
            for (int tj = 0; tj < 2; ++tj) acc[ti][tj] = {0.f, 0.f, 0.f, 0.f};

        const int rstg = tid >> 4;         // 0..31
        const int cstg = (tid & 15) * 8;   // 0..120 (<136)

#pragma unroll
        for (int kh = 0; kh < 2; ++kh) {
            if (kh) __syncthreads();
#pragma unroll
            for (int it = 0; it < 4; ++it) {
                const int r = it * 32 + rstg;
                *(ulonglong2*)&lA[r][cstg] =
                    *(const ulonglong2*)&Abase[(size_t)r * 256 + kh * 128 + cstg];
                *(ulonglong2*)&lB[r][cstg] =
                    *(const ulonglong2*)&Bbase[(size_t)r * 256 + kh * 128 + cstg];
            }
            __syncthreads();

#pragma unroll
            for (int kk = 0; kk < 4; ++kk) {
                s16x8 af[4], bfv[2];
#pragma unroll
                for (int ti = 0; ti < 4; ++ti)
                    af[ti] = *(const s16x8*)&lA[r0 + ti * 16 + lcol][kk * 32 + quad * 8];
#pragma unroll
                for (int tj = 0; tj < 2; ++tj)
                    bfv[tj] = *(const s16x8*)&lB[c0 + tj * 16 + lcol][kk * 32 + quad * 8];
#pragma unroll
                for (int ti = 0; ti < 4; ++ti)
#pragma unroll
                    for (int tj = 0; tj < 2; ++tj)
                        acc[ti][tj] = MF(af[ti], bfv[tj], acc[ti][tj]);
            }
        }

        float bias[2];
#pragma unroll
        for (int tj = 0; tj < 2; ++tj)
            bias[tj] = bcat[dir * 384 + nt * 128 + c0 + tj * 16 + lcol];

        __syncthreads();   // fragment reads done; reuse lA as C staging

        unsigned short* lC = &lA[0][0];
#pragma unroll
        for (int ti = 0; ti < 4; ++ti)
#pragma unroll
            for (int tj = 0; tj < 2; ++tj) {
                const int col = c0 + tj * 16 + lcol;
#pragma unroll
                for (int i = 0; i < 4; ++i)
                    lC[(size_t)(r0 + ti * 16 + 4 * quad + i) * 136 + col] =
                        f2bf(acc[ti][tj][i] + bias[tj]);
            }
        __syncthreads();

        unsigned short* ob = gx_wr + ((size_t)(dir * CT + sl) * 512 + bb) * 384 + nt * 128;
#pragma unroll
        for (int it = 0; it < 4; ++it) {
            const int r = it * 32 + rstg;
            *(ulonglong2*)&ob[(size_t)r * 384 + cstg] =
                *(const ulonglong2*)&lC[(size_t)r * 136 + cstg];
        }
        return;
    }

    // ============================ SCAN role (BC=16) ==========================
    const int dir   = bid >> 5;
    const int chunk = bid & 31;
    const int b0    = chunk * 16;
    const int c     = 16 * wave + lcol;

    const float* whh = dir ? whh_b : whh_f;
    const float* bhh = dir ? bhh_b : bhh_f;

    const float bhr = bhh[c];
    const float bhz = bhh[128 + c];
    const float bhn = bhh[256 + c];

    s16x8 bh[3][4];
#pragma unroll
    for (int p = 0; p < 3; ++p) {
        const int nrow = p * 128 + c;
#pragma unroll
        for (int kk = 0; kk < 4; ++kk) {
            const float* src = &whh[(size_t)nrow * 128 + kk * 32 + quad * 8];
            s16x8 f;
#pragma unroll
            for (int j = 0; j < 8; ++j) f[j] = (short)f2bf(src[j]);
            bh[p][kk] = f;
        }
    }

    const unsigned short* gbase = gx_rd + (size_t)dir * CT * 512 * 384;
    auto loadGX = [&](unsigned short (&G)[12], int sl) {
        const unsigned short* gp = gbase + ((size_t)sl * 512 + b0 + 4 * quad) * 384;
#pragma unroll
        for (int g = 0; g < 3; ++g)
#pragma unroll
            for (int i = 0; i < 4; ++i)
                G[g * 4 + i] = gp[(size_t)i * 384 + g * 128 + c];
    };
    unsigned short G0[12], G1[12];
    loadGX(G0, 0);
    loadGX(G1, 1);

    float hreg[4];
    const int gb2 = tid >> 5;          // 0..15 batch row for LDS init
    const int j0  = (tid & 31) * 4;    // 0..124
    if (first) {
#pragma unroll
        for (int i = 0; i < 4; ++i) hreg[i] = 0.f;
        ushort4 z4; z4.x = 0; z4.y = 0; z4.z = 0; z4.w = 0;
        *(ushort4*)&lds_h[0][gb2][j0] = z4;
    } else {
#pragma unroll
        for (int i = 0; i < 4; ++i)
            hreg[i] = hstate[(size_t)(b0 + 4 * quad + i) * 256 + dir * 128 + c];
        ushort4 hv;
        hv.x = f2bf(hstate[(size_t)(b0 + gb2) * 256 + dir * 128 + j0 + 0]);
        hv.y = f2bf(hstate[(size_t)(b0 + gb2) * 256 + dir * 128 + j0 + 1]);
        hv.z = f2bf(hstate[(size_t)(b0 + gb2) * 256 + dir * 128 + j0 + 2]);
        hv.w = f2bf(hstate[(size_t)(b0 + gb2) * 256 + dir * 128 + j0 + 3]);
        *(ushort4*)&lds_h[0][gb2][j0] = hv;
    }
    __syncthreads();

#define L1C_STEP(S, PAR, G)                                                    \
    do {                                                                       \
        const s16x8 a0 = *(const s16x8*)&lds_h[PAR][lcol][0  + quad * 8];      \
        const s16x8 a1 = *(const s16x8*)&lds_h[PAR][lcol][32 + quad * 8];      \
        const s16x8 a2 = *(const s16x8*)&lds_h[PAR][lcol][64 + quad * 8];      \
        const s16x8 a3 = *(const s16x8*)&lds_h[PAR][lcol][96 + quad * 8];      \
        f32x4 rA = {bhr, bhr, bhr, bhr}, rB = {0.f, 0.f, 0.f, 0.f};            \
        f32x4 zA = {bhz, bhz, bhz, bhz}, zB = {0.f, 0.f, 0.f, 0.f};            \
        f32x4 nA = {bhn, bhn, bhn, bhn}, nB = {0.f, 0.f, 0.f, 0.f};            \
        rA = MF(a0, bh[0][0], rA); zA = MF(a0, bh[1][0], zA);                  \
        nA = MF(a0, bh[2][0], nA);                                             \
        rB = MF(a1, bh[0][1], rB); zB = MF(a1, bh[1][1], zB);                  \
        nB = MF(a1, bh[2][1], nB);                                             \
        rA = MF(a2, bh[0][2], rA); zA = MF(a2, bh[1][2], zA);                  \
        nA = MF(a2, bh[2][2], nA);                                             \
        rB = MF(a3, bh[0][3], rB); zB = MF(a3, bh[1][3], zB);                  \
        nB = MF(a3, bh[2][3], nB);                                             \
        _Pragma("unroll")                                                      \
        for (int i = 0; i < 4; ++i) {                                          \
            const float r = fsig(rA[i] + rB[i] + bf2f(G[i]));                  \
            const float z = fsig(zA[i] + zB[i] + bf2f(G[4 + i]));              \
            const float n = ftanh(bf2f(G[8 + i]) + r * (nA[i] + nB[i]));       \
            hreg[i] = (1.0f - z) * n + z * hreg[i];                            \
            lds_h[PAR ^ 1][4 * quad + i][c] = f2bf(hreg[i]);                   \
        }                                                                      \
        if ((S) < CT - 2) {                                                    \
            loadGX(G, (S) + 2);                                                \
        } else if ((S) == CT - 1) {                                            \
            _Pragma("unroll")                                                  \
            for (int i = 0; i < 4; ++i)                                        \
                hstate[(size_t)(b0 + 4 * quad + i) * 256 + dir * 128 + c] =    \
                    hreg[i];                                                   \
        }                                                                      \
        WG_BARRIER();                                                          \
    } while (0)

    for (int sl = 0; sl < CT; sl += 2) {
        L1C_STEP(sl,     0, G0);
        L1C_STEP(sl + 1, 1, G1);
    }
#undef L1C_STEP
}

// ---------------------------------------------------------------------------
// Fallback layer-1 (fused Gx, verbatim from passing R3) — if no CT fits.
// ---------------------------------------------------------------------------
__global__ __launch_bounds__(THREADS, 1) void gru_l1(
    const unsigned short* __restrict__ y0,
    const float* __restrict__ wih_f, const float* __restrict__ whh_f,
    const float* __restrict__ bih_f, const float* __restrict__ bhh_f,
    const float* __restrict__ wih_b, const float* __restrict__ whh_b,
    const float* __restrict__ bih_b, const float* __restrict__ bhh_b,
    float* __restrict__ finals)
{
    const int tid  = threadIdx.x;
    const int wave = tid >> 6;
    const int lane = tid & 63;
    const int lcol = lane & 15;
    const int quad = lane >> 4;
    const int dir   = blockIdx.x >> 5;
    const int b0    = (blockIdx.x & 31) * 16;
    const int c     = 16 * wave + lcol;

    const float* wih = dir ? wih_b : wih_f;
    const float* whh = dir ? whh_b : whh_f;
    const float* bih = dir ? bih_b : bih_f;
    const float* bhh = dir ? bhh_b : bhh_f;

    __shared__ __align__(16) unsigned short lds_h[2][16][136];

    const float br  = bih[c]       + bhh[c];
    const float bz  = bih[128 + c] + bhh[128 + c];
    const float bnx = bih[256 + c];
    const float bnh = bhh[256 + c];

    s16x8 bh[3][4];
    s16x8 bx[3][8];
#pragma unroll
    for (int p = 0; p < 3; ++p) {
        const int nrow = p * 128 + c;
#pragma unroll
        for (int kk = 0; kk < 4; ++kk) {
            const float* src = &whh[(size_t)nrow * 128 + kk * 32 + quad * 8];
            s16x8 f;
#pragma unroll
            for (int j = 0; j < 8; ++j) f[j] = (short)f2bf(src[j]);
            bh[p][kk] = f;
        }
#pragma unroll
        for (int kk = 0; kk < 8; ++kk) {
            const float* src = &wih[(size_t)nrow * 256 + kk * 32 + quad * 8];
            s16x8 f;
#pragma unroll
            for (int j = 0; j < 8; ++j) f[j] = (short)f2bf(src[j]);
            bx[p][kk] = f;
        }
    }

    auto loadP = [&](s16x8 (&P)[8], int t) {
        const unsigned short* pb = y0 + ((size_t)t * Bb + b0 + lcol) * 256 + quad * 8;
#pragma unroll
        for (int kk = 0; kk < 8; ++kk) P[kk] = *(const s16x8*)(pb + kk * 32);
    };
    s16x8 P0[8], P1[8];
    loadP(P0, dir ? 511 : 0);
    loadP(P1, dir ? 510 : 1);

    f32x4 accr = {br, br, br, br};
    f32x4 accz = {bz, bz, bz, bz};
    f32x4 accnx = {bnx, bnx, bnx, bnx};
#pragma unroll
    for (int kk = 0; kk < 8; ++kk) {
        accr  = MF(P0[kk], bx[0][kk], accr);
        accz  = MF(P0[kk], bx[1][kk], accz);
        accnx = MF(P0[kk], bx[2][kk], accnx);
    }
    loadP(P0, dir ? 509 : 2);

    float hreg[4] = {0.f, 0.f, 0.f, 0.f};
    for (int idx = tid; idx < 2 * 16 * 136; idx += THREADS)
        ((unsigned short*)lds_h)[idx] = 0;
    __syncthreads();

#define L1_STEP(S, PAR, PN)                                                    \
    do {                                                                       \
        const s16x8 a0 = *(const s16x8*)&lds_h[PAR][lcol][0  + quad * 8];      \
        const s16x8 a1 = *(const s16x8*)&lds_h[PAR][lcol][32 + quad * 8];      \
        const s16x8 a2 = *(const s16x8*)&lds_h[PAR][lcol][64 + quad * 8];      \
        const s16x8 a3 = *(const s16x8*)&lds_h[PAR][lcol][96 + quad * 8];      \
        f32x4 acchn = {bnh, bnh, bnh, bnh};                                    \
        accr = MF(a0, bh[0][0], accr); accz = MF(a0, bh[1][0], accz);          \
        acchn = MF(a0, bh[2][0], acchn);                                       \
        accr = MF(a1, bh[0][1], accr); accz = MF(a1, bh[1][1], accz);          \
        acchn = MF(a1, bh[2][1], acchn);                                       \
        accr = MF(a2, bh[0][2], accr); accz = MF(a2, bh[1][2], accz);          \
        acchn = MF(a2, bh[2][2], acchn);                                       \
        accr = MF(a3, bh[0][3], accr); accz = MF(a3, bh[1][3], accz);          \
        acchn = MF(a3, bh[2][3], acchn);                                       \
        _Pragma("unroll")                                                      \
        for (int i = 0; i < 4; ++i) {                                          \
            const float r = fsig(accr[i]);                                     \
            const float z = fsig(accz[i]);                                     \
            const float n = ftanh(accnx[i] + r * acchn[i]);                    \
            hreg[i] = (1.0f - z) * n + z * hreg[i];                            \
            lds_h[PAR ^ 1][4 * quad + i][c] = f2bf(hreg[i]);                   \
        }                                                                      \
        if ((S) < 511) {                                                       \
            accr = {br, br, br, br}; accz = {bz, bz, bz, bz};                  \
            accnx = {bnx, bnx, bnx, bnx};                                      \
            _Pragma("unroll")                                                  \
            for (int kk = 0; kk < 8; ++kk) {                                   \
                accr  = MF(PN[kk], bx[0][kk], accr);                           \
                accz  = MF(PN[kk], bx[1][kk], accz);                           \
                accnx = MF(PN[kk], bx[2][kk], accnx);                          \
            }                                                                  \
            int sp = (S) + 3; if (sp > 511) sp = 511;                          \
            loadP(PN, dir ? (511 - sp) : sp);                                  \
        } else {                                                               \
            _Pragma("unroll")                                                  \
            for (int i = 0; i < 4; ++i)                                        \
                finals[(size_t)(b0 + 4 * quad + i) * 256 + dir * 128 + c] =    \
                    hreg[i];                                                   \
        }                                                                      \
        WG_BARRIER();                                                          \
    } while (0)

    for (int s = 0; s < Tt; s += 2) {
        L1_STEP(s,     0, P1);
        L1_STEP(s + 1, 1, P0);
    }
#undef L1_STEP
}

// ---------------------------------------------------------------------------
// Layer 0 scan, R14: BC=4, bias-only MFMA init, A-ROW REPLICATION (read row
// lcol&3) -> every lane's reg i = batch row i -> select acc[quad], NO shfl.
// Own-row x-projection added after selection.
// ---------------------------------------------------------------------------
__global__ __launch_bounds__(THREADS, 1) void gru_l0(
    const float* __restrict__ x,
    const float* __restrict__ wih_f, const float* __restrict__ whh_f,
    const float* __restrict__ bih_f, const float* __restrict__ bhh_f,
    const float* __restrict__ wih_b, const float* __restrict__ whh_b,
    const float* __restrict__ bih_b, const float* __restrict__ bhh_b,
    unsigned short* __restrict__ y0)
{
    const int tid  = threadIdx.x;
    const int wave = tid >> 6;
    const int lane = tid & 63;
    const int lcol = lane & 15;
    const int quad = lane >> 4;
    const int arow = lcol & 3;        // replicated A row source
    const int dir   = blockIdx.x >> 7;
    const int chunk = blockIdx.x & 127;
    const int b0    = chunk * 4;
    const int c     = 16 * wave + lcol;

    const float* wih = dir ? wih_b : wih_f;
    const float* whh = dir ? whh_b : whh_f;
    const float* bih = dir ? bih_b : bih_f;
    const float* bhh = dir ? bhh_b : bhh_f;

    __shared__ __align__(16) unsigned short lds_h[2][16][136];

    const float brs  = bih[c]       + bhh[c];
    const float bzs  = bih[128 + c] + bhh[128 + c];
    const float bnxs = bih[256 + c];
    const float bnh  = bhh[256 + c];

    float wr[4], wz[4], wn[4];
#pragma unroll
    for (int f = 0; f < 4; ++f) {
        wr[f] = wih[(c)       * 4 + f];
        wz[f] = wih[(128 + c) * 4 + f];
        wn[f] = wih[(256 + c) * 4 + f];
    }

    s16x8 bh[3][4];
#pragma unroll
    for (int p = 0; p < 3; ++p) {
        const int nrow = p * 128 + c;
#pragma unroll
        for (int kk = 0; kk < 4; ++kk) {
            const float* src = &whh[(size_t)nrow * 128 + kk * 32 + quad * 8];
            s16x8 f;
#pragma unroll
            for (int j = 0; j < 8; ++j) f[j] = (short)f2bf(src[j]);
            bh[p][kk] = f;
        }
    }

    auto loadX = [&](float4& X, int t) {
        X = *(const float4*)&x[((size_t)(b0 + quad) * Tt + t) * 4];
    };
    float4 X0, X1;
    loadX(X0, dir ? 511 : 0);
    loadX(X1, dir ? 510 : 1);

    float hmine = 0.f;   // this lane's h element: (row=quad, col=c)
    for (int idx = tid; idx < 2 * 16 * 136; idx += THREADS)
        ((unsigned short*)lds_h)[idx] = 0;
    __syncthreads();

    const int orow = tid >> 7;        // y0 store: row 0..3
    const int ocol = tid & 127;       // col 0..127

#define L0_STEP(S, PAR, XC)                                                    \
    do {                                                                       \
        const int t = dir ? (511 - (S)) : (S);                                 \
        const s16x8 a0 = *(const s16x8*)&lds_h[PAR][arow][0  + quad * 8];      \
        const s16x8 a1 = *(const s16x8*)&lds_h[PAR][arow][32 + quad * 8];      \
        const s16x8 a2 = *(const s16x8*)&lds_h[PAR][arow][64 + quad * 8];      \
        const s16x8 a3 = *(const s16x8*)&lds_h[PAR][arow][96 + quad * 8];      \
        f32x4 accr  = {brs, brs, brs, brs};                                    \
        f32x4 accz  = {bzs, bzs, bzs, bzs};                                    \
        f32x4 acchn = {bnh, bnh, bnh, bnh};                                    \
        accr = MF(a0, bh[0][0], accr); accz = MF(a0, bh[1][0], accz);          \
        acchn = MF(a0, bh[2][0], acchn);                                       \
        accr = MF(a1, bh[0][1], accr); accz = MF(a1, bh[1][1], accz);          \
        acchn = MF(a1, bh[2][1], acchn);                                       \
        accr = MF(a2, bh[0][2], accr); accz = MF(a2, bh[1][2], accz);          \
        acchn = MF(a2, bh[2][2], acchn);                                       \
        accr = MF(a3, bh[0][3], accr); accz = MF(a3, bh[1][3], accz);          \
        acchn = MF(a3, bh[2][3], acchn);                                       \
        const float xr = XC.x * wr[0] + XC.y * wr[1]                           \
                       + XC.z * wr[2] + XC.w * wr[3];                          \
        const float xz = XC.x * wz[0] + XC.y * wz[1]                           \
                       + XC.z * wz[2] + XC.w * wz[3];                          \
        const float xn = bnxs + XC.x * wn[0] + XC.y * wn[1]                    \
                       + XC.z * wn[2] + XC.w * wn[3];                          \
        /* reg i holds batch row i for every lane: select own row = quad */    \
        const float pr = quad == 0 ? accr[0] : quad == 1 ? accr[1]             \
                       : quad == 2 ? accr[2] : accr[3];                        \
        const float pz = quad == 0 ? accz[0] : quad == 1 ? accz[1]             \
                       : quad == 2 ? accz[2] : accz[3];                        \
        const float ph = quad == 0 ? acchn[0] : quad == 1 ? acchn[1]           \
                       : quad == 2 ? acchn[2] : acchn[3];                      \
        {                                                                      \
            const float r = fsig(pr + xr);                                     \
            const float z = fsig(pz + xz);                                     \
            const float n = ftanh(xn + r * ph);                                \
            hmine = (1.0f - z) * n + z * hmine;                                \
            lds_h[PAR ^ 1][quad][c] = f2bf(hmine);                             \
        }                                                                      \
        if ((S) < 510) {                                                       \
            loadX(XC, dir ? (511 - ((S) + 2)) : ((S) + 2));                    \
        }                                                                      \
        WG_BARRIER();                                                          \
        {                                                                      \
            y0[((size_t)t * Bb + b0 + orow) * 256 + dir * 128 + ocol] =        \
                lds_h[PAR ^ 1][orow][ocol];                                    \
        }                                                                      \
    } while (0)

    for (int s = 0; s < Tt; s += 2) {
        L0_STEP(s,     0, X0);
        L0_STEP(s + 1, 1, X1);
    }
#undef L0_STEP
}

// ---------------------------------------------------------------------------
// FC head: out = relu(finals @ fc1^T + b1) @ fc2^T + b2   [512,256]->[512,2]
// ---------------------------------------------------------------------------
__global__ __launch_bounds__(128) void fc_head(
    const float* __restrict__ finals,
    const float* __restrict__ fc1w, const float* __restrict__ fc1b,
    const float* __restrict__ fc2w, const float* __restrict__ fc2b,
    float* __restrict__ out)
{
    __shared__ float s_in[256];
    __shared__ float s_h1[128];
    const int b = blockIdx.x, tid = threadIdx.x;
    s_in[tid]       = finals[(size_t)b * 256 + tid];
    s_in[tid + 128] = finals[(size_t)b * 256 + 128 + tid];
    __syncthreads();
    float acc = fc1b[tid];
    const float* wrow = &fc1w[tid * 256];
#pragma unroll 8
    for (int i = 0; i < 256; ++i) acc += s_in[i] * wrow[i];
    s_h1[tid] = fmaxf(acc, 0.0f);
    __syncthreads();
    if (tid < 2) {
        float a = fc2b[tid];
        const float* w2 = &fc2w[tid * 128];
#pragma unroll 8
        for (int i = 0; i < 128; ++i) a += s_h1[i] * w2[i];
        out[b * 2 + tid] = a;
    }
}

extern "C" void kernel_launch(void* const* d_in, const int* in_sizes, int n_in,
                              void* d_out, int out_size, void* d_ws, size_t ws_size,
                              hipStream_t stream) {
    const float* x      = (const float*)d_in[0];
    const float* wih0f  = (const float*)d_in[1];
    const float* whh0f  = (const float*)d_in[2];
    const float* bih0f  = (const float*)d_in[3];
    const float* bhh0f  = (const float*)d_in[4];
    const float* wih0b  = (const float*)d_in[5];
    const float* whh0b  = (const float*)d_in[6];
    const float* bih0b  = (const float*)d_in[7];
    const float* bhh0b  = (const float*)d_in[8];
    const float* wih1f  = (const float*)d_in[9];
    const float* whh1f  = (const float*)d_in[10];
    const float* bih1f  = (const float*)d_in[11];
    const float* bhh1f  = (const float*)d_in[12];
    const float* wih1b  = (const float*)d_in[13];
    const float* whh1b  = (const float*)d_in[14];
    const float* bih1b  = (const float*)d_in[15];
    const float* bhh1b  = (const float*)d_in[16];
    const float* fc1w   = (const float*)d_in[17];
    const float* fc1b   = (const float*)d_in[18];
    const float* fc2w   = (const float*)d_in[19];
    const float* fc2b   = (const float*)d_in[20];

    const size_t Y0SZ = 134217728ull;   // y0 bf16 [512][512][256]
    const size_t HSSZ = 524288ull;      // hstate/finals f32 [512][256]
    const size_t WCSZ = 393216ull;      // wcat bf16 [768][256]
    const size_t BCSZ = 3072ull;        // bcat f32 [768]
    const size_t GX_PER_SL = 786432ull; // per sl: 2 dirs * 512 * 384 bf16 * 2B
    const size_t BASE = Y0SZ + HSSZ + WCSZ + BCSZ;

    unsigned short* y0 = (unsigned short*)d_ws;
    float*  hstate = (float*)((char*)d_ws + Y0SZ);
    unsigned short* wcat = (unsigned short*)((char*)d_ws + Y0SZ + HSSZ);
    float*  bcat   = (float*)((char*)d_ws + Y0SZ + HSSZ + WCSZ);
    unsigned short* gx0 = (unsigned short*)((char*)d_ws + BASE);
    float* out = (float*)d_out;

    const int cts[6] = {128, 64, 32, 16, 8, 4};
    int CT = 0, fused = 0;
    for (int i = 0; i < 6; ++i)
        if (BASE + 2ull * cts[i] * GX_PER_SL <= ws_size) { CT = cts[i]; fused = 1; break; }
    if (!CT)
        for (int i = 0; i < 6; ++i)
            if (BASE + (size_t)cts[i] * GX_PER_SL <= ws_size) { CT = cts[i]; break; }

    if (CT > 0) {
        unsigned short* gxb[2];
        gxb[0] = gx0;
        gxb[1] = fused ? (unsigned short*)((char*)gx0 + (size_t)CT * GX_PER_SL) : gx0;

        w_prep<<<dim3(768), dim3(256), 0, stream>>>(wih1f, wih1b, bih1f, bih1b, wcat, bcat);
        gru_l0<<<dim3(256), dim3(THREADS), 0, stream>>>(
            x, wih0f, whh0f, bih0f, bhh0f, wih0b, whh0b, bih0b, bhh0b, y0);
        const int n = Tt / CT;
        if (fused) {
            // prologue: gemm chunk 0 -> buf0
            l1_step<<<dim3(24 * CT), dim3(THREADS), 0, stream>>>(
                y0, wcat, bcat, gxb[0], gxb[0],
                whh1f, bhh1f, whh1b, bhh1b, hstate, CT, 0, 0, 1);
            for (int k = 0; k < n; ++k) {
                const int ng = (k + 1 < n) ? 24 * CT : 0;
                l1_step<<<dim3(64 + ng), dim3(THREADS), 0, stream>>>(
                    y0, wcat, bcat, gxb[k & 1], gxb[(k + 1) & 1],
                    whh1f, bhh1f, whh1b, bhh1b, hstate, CT, k + 1, 64, (k == 0) ? 1 : 0);
            }
        } else {
            for (int k = 0; k < n; ++k) {
                l1_step<<<dim3(24 * CT), dim3(THREADS), 0, stream>>>(
                    y0, wcat, bcat, gxb[0], gxb[0],
                    whh1f, bhh1f, whh1b, bhh1b, hstate, CT, k, 0, 1);
                l1_step<<<dim3(64), dim3(THREADS), 0, stream>>>(
                    y0, wcat, bcat, gxb[0], gxb[0],
                    whh1f, bhh1f, whh1b, bhh1b, hstate, CT, 0, 64, (k == 0) ? 1 : 0);
            }
        }
        fc_head<<<dim3(Bb), dim3(128), 0, stream>>>(hstate, fc1w, fc1b, fc2w, fc2b, out);
    } else {
        float* finals = (float*)((char*)d_ws + Y0SZ);
        gru_l0<<<dim3(256), dim3(THREADS), 0, stream>>>(
            x, wih0f, whh0f, bih0f, bhh0f, wih0b, whh0b, bih0b, bhh0b, y0);
        gru_l1<<<dim3(64), dim3(THREADS), 0, stream>>>(
            y0, wih1f, whh1f, bih1f, bhh1f, wih1b, whh1b, bih1b, bhh1b, finals);
        fc_head<<<dim3(Bb), dim3(128), 0, stream>>>(finals, fc1w, fc1b, fc2w, fc2b, out);
    }
}

// Round 15
// 1003.647 us; speedup vs baseline: 1.2075x; 1.0005x over previous
//
#include <hip/hip_runtime.h>
#include <stdint.h>

// GRUClassifier: 2-layer bidir GRU (H=128, T=512, B=512) + FC head.
// R15 = R14 + gx layout transposed to [slot][gc][b] (b innermost): the l1
// scan's per-step G fetch becomes 3 ushort4 loads (rows b0+4q..+3 contiguous)
// instead of 12 scalar loads. Gemm stages C transposed in LDS (same LDS
// round-trip, swapped indices) and stores gc-major rows coalesced along b.
// gru_l0 (A-row replication, no shfl) and all else verbatim R14.

#define Tt 512
#define Bb 512
#define THREADS 512

using s16x8 = __attribute__((ext_vector_type(8))) short;  // 8 bf16 (4 VGPRs)
using f32x4 = __attribute__((ext_vector_type(4))) float;

#define MF(a, b, c) __builtin_amdgcn_mfma_f32_16x16x32_bf16((a), (b), (c), 0, 0, 0)

__device__ __forceinline__ unsigned short f2bf(float f) {
    union { float f; unsigned int u; } v; v.f = f;
    unsigned int u = v.u;
    u += 0x7fffu + ((u >> 16) & 1u);   // RNE
    return (unsigned short)(u >> 16);
}
__device__ __forceinline__ float bf2f(unsigned short h) {
    union { unsigned int u; float f; } v; v.u = ((unsigned int)h) << 16;
    return v.f;
}

__device__ __forceinline__ float fsig(float x) {
    return __builtin_amdgcn_rcpf(1.0f + __expf(-x));
}
__device__ __forceinline__ float ftanh(float x) {
    return 2.0f * __builtin_amdgcn_rcpf(1.0f + __expf(-2.0f * x)) - 1.0f;
}

// Raw workgroup barrier: drains LDS ops only; in-flight global register
// prefetch loads survive it (vmcnt not drained).
#define WG_BARRIER() asm volatile("s_waitcnt lgkmcnt(0)\n\ts_barrier" ::: "memory")

// ---------------------------------------------------------------------------
// w_prep: pack W_ih1 (both dirs) to bf16 [768][256] + bias concat [768].
// ---------------------------------------------------------------------------
__global__ void w_prep(const float* __restrict__ wihf, const float* __restrict__ wihb,
                       const float* __restrict__ bihf, const float* __restrict__ bihb,
                       unsigned short* __restrict__ wcat, float* __restrict__ bcat)
{
    const int n = blockIdx.x;   // 0..767
    const int k = threadIdx.x;  // 0..255
    const float* src = (n < 384) ? &wihf[(size_t)n * 256] : &wihb[(size_t)(n - 384) * 256];
    wcat[(size_t)n * 256 + k] = f2bf(src[k]);
    if (k == 0) bcat[n] = (n < 384) ? bihf[n] : bihb[n - 384];
}

// ---------------------------------------------------------------------------
// l1_step: fused chunk kernel.
//   blocks [0,nscan): scan role (BC=16), reads gx_rd.
//   blocks [nscan,..): gemm role, chunk kgemm, writes gx_wr.
//   gx layout: gx[((dir*CT + sl)*384 + gc)*512 + b]   (gc = gate*128 + col)
//   -> scan reads a lane's 4 batch rows as ONE ushort4.
// ---------------------------------------------------------------------------
__global__ __launch_bounds__(THREADS) void l1_step(
    const unsigned short* __restrict__ y0,
    const unsigned short* __restrict__ wcat,
    const float* __restrict__ bcat,
    const unsigned short* __restrict__ gx_rd,
    unsigned short* __restrict__ gx_wr,
    const float* __restrict__ whh_f, const float* __restrict__ bhh_f,
    const float* __restrict__ whh_b, const float* __restrict__ bhh_b,
    float* __restrict__ hstate,
    int CT, int kgemm, int nscan, int first)
{
    const int bid  = blockIdx.x;
    const int tid  = threadIdx.x;
    const int wave = tid >> 6;
    const int lane = tid & 63;
    const int lcol = lane & 15;
    const int quad = lane >> 4;

    __shared__ __align__(16) unsigned short lA[128][136];
    __shared__ __align__(16) unsigned short lB[128][136];
    __shared__ __align__(16) unsigned short lds_h[2][16][136];

    if (bid >= nscan) {
        // =============================== GEMM role ===========================
        int gb = bid - nscan;
        const int nt = gb % 3;  gb /= 3;
        const int bt = gb & 3;  gb >>= 2;
        const int sl = gb % CT;
        const int dir = gb / CT;
        const int s  = kgemm * CT + sl;
        const int t  = dir ? (511 - s) : s;
        const int bb = bt << 7;

        const unsigned short* Abase = y0 + ((size_t)t * 512 + bb) * 256;
        const unsigned short* Bbase = wcat + ((size_t)dir * 384 + nt * 128) * 256;

        const int r0 = (wave >> 2) * 64;   // 0 or 64  (batch rows)
        const int c0 = (wave & 3) * 32;    // 0,32,64,96 (gate cols)

        f32x4 acc[4][2];
#pragma unroll
        for (int ti = 0; ti < 4; ++ti)
#pragma unroll
            for (int tj = 0; tj < 2; ++tj) acc[ti][tj] = {0.f, 0.f, 0.f, 0.f};

        const int rstg = tid >> 4;         // 0..31
        const int cstg = (tid & 15) * 8;   // 0..120 (<136)

#pragma unroll
        for (int kh = 0; kh < 2; ++kh) {
            if (kh) __syncthreads();
#pragma unroll
            for (int it = 0; it < 4; ++it) {
                const int r = it * 32 + rstg;
                *(ulonglong2*)&lA[r][cstg] =
                    *(const ulonglong2*)&Abase[(size_t)r * 256 + kh * 128 + cstg];
                *(ulonglong2*)&lB[r][cstg] =
                    *(const ulonglong2*)&Bbase[(size_t)r * 256 + kh * 128 + cstg];
            }
            __syncthreads();

#pragma unroll
            for (int kk = 0; kk < 4; ++kk) {
                s16x8 af[4], bfv[2];
#pragma unroll
                for (int ti = 0; ti < 4; ++ti)
                    af[ti] = *(const s16x8*)&lA[r0 + ti * 16 + lcol][kk * 32 + quad * 8];
#pragma unroll
                for (int tj = 0; tj < 2; ++tj)
                    bfv[tj] = *(const s16x8*)&lB[c0 + tj * 16 + lcol][kk * 32 + quad * 8];
#pragma unroll
                for (int ti = 0; ti < 4; ++ti)
#pragma unroll
                    for (int tj = 0; tj < 2; ++tj)
                        acc[ti][tj] = MF(af[ti], bfv[tj], acc[ti][tj]);
            }
        }

        float bias[2];
#pragma unroll
        for (int tj = 0; tj < 2; ++tj)
            bias[tj] = bcat[dir * 384 + nt * 128 + c0 + tj * 16 + lcol];

        __syncthreads();   // fragment reads done; reuse lA as TRANSPOSED C

        // stage C transposed: lC[col][row], row stride 136 (rows 0..127)
        unsigned short* lC = &lA[0][0];
#pragma unroll
        for (int ti = 0; ti < 4; ++ti)
#pragma unroll
            for (int tj = 0; tj < 2; ++tj) {
                const int col = c0 + tj * 16 + lcol;
#pragma unroll
                for (int i = 0; i < 4; ++i)
                    lC[(size_t)col * 136 + (r0 + ti * 16 + 4 * quad + i)] =
                        f2bf(acc[ti][tj][i] + bias[tj]);
            }
        __syncthreads();

        // store gc-major: ob[gcL*512 + local_b], contiguous along b
        unsigned short* ob =
            gx_wr + ((size_t)(dir * CT + sl) * 384 + nt * 128) * 512 + bb;
        const int gcL = tid >> 2;          // 0..127
        const int q4  = (tid & 3) * 32;    // 0,32,64,96
#pragma unroll
        for (int j = 0; j < 4; ++j) {
            const int off = q4 + j * 8;
            *(ulonglong2*)&ob[(size_t)gcL * 512 + off] =
                *(const ulonglong2*)&lC[(size_t)gcL * 136 + off];
        }
        return;
    }

    // ============================ SCAN role (BC=16) ==========================
    const int dir   = bid >> 5;
    const int chunk = bid & 31;
    const int b0    = chunk * 16;
    const int c     = 16 * wave + lcol;

    const float* whh = dir ? whh_b : whh_f;
    const float* bhh = dir ? bhh_b : bhh_f;

    const float bhr = bhh[c];
    const float bhz = bhh[128 + c];
    const float bhn = bhh[256 + c];

    s16x8 bh[3][4];
#pragma unroll
    for (int p = 0; p < 3; ++p) {
        const int nrow = p * 128 + c;
#pragma unroll
        for (int kk = 0; kk < 4; ++kk) {
            const float* src = &whh[(size_t)nrow * 128 + kk * 32 + quad * 8];
            s16x8 f;
#pragma unroll
            for (int j = 0; j < 8; ++j) f[j] = (short)f2bf(src[j]);
            bh[p][kk] = f;
        }
    }

    // G loads: gate g, col c, rows b0+4q..+3 contiguous -> one ushort4 each.
    const unsigned short* gbase = gx_rd + (size_t)dir * CT * 384 * 512;
    auto loadGX = [&](ushort4 (&G)[3], int sl) {
        const unsigned short* gp = gbase + (size_t)sl * 384 * 512;
#pragma unroll
        for (int g = 0; g < 3; ++g)
            G[g] = *(const ushort4*)&gp[(size_t)(g * 128 + c) * 512 + b0 + 4 * quad];
    };
    ushort4 G0[3], G1[3];
    loadGX(G0, 0);
    loadGX(G1, 1);

    float hreg[4];
    const int gb2 = tid >> 5;          // 0..15 batch row for LDS init
    const int j0  = (tid & 31) * 4;    // 0..124
    if (first) {
#pragma unroll
        for (int i = 0; i < 4; ++i) hreg[i] = 0.f;
        ushort4 z4; z4.x = 0; z4.y = 0; z4.z = 0; z4.w = 0;
        *(ushort4*)&lds_h[0][gb2][j0] = z4;
    } else {
#pragma unroll
        for (int i = 0; i < 4; ++i)
            hreg[i] = hstate[(size_t)(b0 + 4 * quad + i) * 256 + dir * 128 + c];
        ushort4 hv;
        hv.x = f2bf(hstate[(size_t)(b0 + gb2) * 256 + dir * 128 + j0 + 0]);
        hv.y = f2bf(hstate[(size_t)(b0 + gb2) * 256 + dir * 128 + j0 + 1]);
        hv.z = f2bf(hstate[(size_t)(b0 + gb2) * 256 + dir * 128 + j0 + 2]);
        hv.w = f2bf(hstate[(size_t)(b0 + gb2) * 256 + dir * 128 + j0 + 3]);
        *(ushort4*)&lds_h[0][gb2][j0] = hv;
    }
    __syncthreads();

#define L1C_STEP(S, PAR, G)                                                    \
    do {                                                                       \
        const s16x8 a0 = *(const s16x8*)&lds_h[PAR][lcol][0  + quad * 8];      \
        const s16x8 a1 = *(const s16x8*)&lds_h[PAR][lcol][32 + quad * 8];      \
        const s16x8 a2 = *(const s16x8*)&lds_h[PAR][lcol][64 + quad * 8];      \
        const s16x8 a3 = *(const s16x8*)&lds_h[PAR][lcol][96 + quad * 8];      \
        f32x4 rA = {bhr, bhr, bhr, bhr}, rB = {0.f, 0.f, 0.f, 0.f};            \
        f32x4 zA = {bhz, bhz, bhz, bhz}, zB = {0.f, 0.f, 0.f, 0.f};            \
        f32x4 nA = {bhn, bhn, bhn, bhn}, nB = {0.f, 0.f, 0.f, 0.f};            \
        rA = MF(a0, bh[0][0], rA); zA = MF(a0, bh[1][0], zA);                  \
        nA = MF(a0, bh[2][0], nA);                                             \
        rB = MF(a1, bh[0][1], rB); zB = MF(a1, bh[1][1], zB);                  \
        nB = MF(a1, bh[2][1], nB);                                             \
        rA = MF(a2, bh[0][2], rA); zA = MF(a2, bh[1][2], zA);                  \
        nA = MF(a2, bh[2][2], nA);                                             \
        rB = MF(a3, bh[0][3], rB); zB = MF(a3, bh[1][3], zB);                  \
        nB = MF(a3, bh[2][3], nB);                                             \
        const unsigned short* gr_ = (const unsigned short*)&G[0];              \
        const unsigned short* gz_ = (const unsigned short*)&G[1];              \
        const unsigned short* gn_ = (const unsigned short*)&G[2];              \
        _Pragma("unroll")                                                      \
        for (int i = 0; i < 4; ++i) {                                          \
            const float r = fsig(rA[i] + rB[i] + bf2f(gr_[i]));                \
            const float z = fsig(zA[i] + zB[i] + bf2f(gz_[i]));                \
            const float n = ftanh(bf2f(gn_[i]) + r * (nA[i] + nB[i]));         \
            hreg[i] = (1.0f - z) * n + z * hreg[i];                            \
            lds_h[PAR ^ 1][4 * quad + i][c] = f2bf(hreg[i]);                   \
        }                                                                      \
        if ((S) < CT - 2) {                                                    \
            loadGX(G, (S) + 2);                                                \
        } else if ((S) == CT - 1) {                                            \
            _Pragma("unroll")                                                  \
            for (int i = 0; i < 4; ++i)                                        \
                hstate[(size_t)(b0 + 4 * quad + i) * 256 + dir * 128 + c] =    \
                    hreg[i];                                                   \
        }                                                                      \
        WG_BARRIER();                                                          \
    } while (0)

    for (int sl = 0; sl < CT; sl += 2) {
        L1C_STEP(sl,     0, G0);
        L1C_STEP(sl + 1, 1, G1);
    }
#undef L1C_STEP
}

// ---------------------------------------------------------------------------
// Fallback layer-1 (fused Gx, verbatim from passing R3) — if no CT fits.
// ---------------------------------------------------------------------------
__global__ __launch_bounds__(THREADS, 1) void gru_l1(
    const unsigned short* __restrict__ y0,
    const float* __restrict__ wih_f, const float* __restrict__ whh_f,
    const float* __restrict__ bih_f, const float* __restrict__ bhh_f,
    const float* __restrict__ wih_b, const float* __restrict__ whh_b,
    const float* __restrict__ bih_b, const float* __restrict__ bhh_b,
    float* __restrict__ finals)
{
    const int tid  = threadIdx.x;
    const int wave = tid >> 6;
    const int lane = tid & 63;
    const int lcol = lane & 15;
    const int quad = lane >> 4;
    const int dir   = blockIdx.x >> 5;
    const int b0    = (blockIdx.x & 31) * 16;
    const int c     = 16 * wave + lcol;

    const float* wih = dir ? wih_b : wih_f;
    const float* whh = dir ? whh_b : whh_f;
    const float* bih = dir ? bih_b : bih_f;
    const float* bhh = dir ? bhh_b : bhh_f;

    __shared__ __align__(16) unsigned short lds_h[2][16][136];

    const float br  = bih[c]       + bhh[c];
    const float bz  = bih[128 + c] + bhh[128 + c];
    const float bnx = bih[256 + c];
    const float bnh = bhh[256 + c];

    s16x8 bh[3][4];
    s16x8 bx[3][8];
#pragma unroll
    for (int p = 0; p < 3; ++p) {
        const int nrow = p * 128 + c;
#pragma unroll
        for (int kk = 0; kk < 4; ++kk) {
            const float* src = &whh[(size_t)nrow * 128 + kk * 32 + quad * 8];
            s16x8 f;
#pragma unroll
            for (int j = 0; j < 8; ++j) f[j] = (short)f2bf(src[j]);
            bh[p][kk] = f;
        }
#pragma unroll
        for (int kk = 0; kk < 8; ++kk) {
            const float* src = &wih[(size_t)nrow * 256 + kk * 32 + quad * 8];
            s16x8 f;
#pragma unroll
            for (int j = 0; j < 8; ++j) f[j] = (short)f2bf(src[j]);
            bx[p][kk] = f;
        }
    }

    auto loadP = [&](s16x8 (&P)[8], int t) {
        const unsigned short* pb = y0 + ((size_t)t * Bb + b0 + lcol) * 256 + quad * 8;
#pragma unroll
        for (int kk = 0; kk < 8; ++kk) P[kk] = *(const s16x8*)(pb + kk * 32);
    };
    s16x8 P0[8], P1[8];
    loadP(P0, dir ? 511 : 0);
    loadP(P1, dir ? 510 : 1);

    f32x4 accr = {br, br, br, br};
    f32x4 accz = {bz, bz, bz, bz};
    f32x4 accnx = {bnx, bnx, bnx, bnx};
#pragma unroll
    for (int kk = 0; kk < 8; ++kk) {
        accr  = MF(P0[kk], bx[0][kk], accr);
        accz  = MF(P0[kk], bx[1][kk], accz);
        accnx = MF(P0[kk], bx[2][kk], accnx);
    }
    loadP(P0, dir ? 509 : 2);

    float hreg[4] = {0.f, 0.f, 0.f, 0.f};
    for (int idx = tid; idx < 2 * 16 * 136; idx += THREADS)
        ((unsigned short*)lds_h)[idx] = 0;
    __syncthreads();

#define L1_STEP(S, PAR, PN)                                                    \
    do {                                                                       \
        const s16x8 a0 = *(const s16x8*)&lds_h[PAR][lcol][0  + quad * 8];      \
        const s16x8 a1 = *(const s16x8*)&lds_h[PAR][lcol][32 + quad * 8];      \
        const s16x8 a2 = *(const s16x8*)&lds_h[PAR][lcol][64 + quad * 8];      \
        const s16x8 a3 = *(const s16x8*)&lds_h[PAR][lcol][96 + quad * 8];      \
        f32x4 acchn = {bnh, bnh, bnh, bnh};                                    \
        accr = MF(a0, bh[0][0], accr); accz = MF(a0, bh[1][0], accz);          \
        acchn = MF(a0, bh[2][0], acchn);                                       \
        accr = MF(a1, bh[0][1], accr); accz = MF(a1, bh[1][1], accz);          \
        acchn = MF(a1, bh[2][1], acchn);                                       \
        accr = MF(a2, bh[0][2], accr); accz = MF(a2, bh[1][2], accz);          \
        acchn = MF(a2, bh[2][2], acchn);                                       \
        accr = MF(a3, bh[0][3], accr); accz = MF(a3, bh[1][3], accz);          \
        acchn = MF(a3, bh[2][3], acchn);                                       \
        _Pragma("unroll")                                                      \
        for (int i = 0; i < 4; ++i) {                                          \
            const float r = fsig(accr[i]);                                     \
            const float z = fsig(accz[i]);                                     \
            const float n = ftanh(accnx[i] + r * acchn[i]);                    \
            hreg[i] = (1.0f - z) * n + z * hreg[i];                            \
            lds_h[PAR ^ 1][4 * quad + i][c] = f2bf(hreg[i]);                   \
        }                                                                      \
        if ((S) < 511) {                                                       \
            accr = {br, br, br, br}; accz = {bz, bz, bz, bz};                  \
            accnx = {bnx, bnx, bnx, bnx};                                      \
            _Pragma("unroll")                                                  \
            for (int kk = 0; kk < 8; ++kk) {                                   \
                accr  = MF(PN[kk], bx[0][kk], accr);                           \
                accz  = MF(PN[kk], bx[1][kk], accz);                           \
                accnx = MF(PN[kk], bx[2][kk], accnx);                          \
            }                                                                  \
            int sp = (S) + 3; if (sp > 511) sp = 511;                          \
            loadP(PN, dir ? (511 - sp) : sp);                                  \
        } else {                                                               \
            _Pragma("unroll")                                                  \
            for (int i = 0; i < 4; ++i)                                        \
                finals[(size_t)(b0 + 4 * quad + i) * 256 + dir * 128 + c] =    \
                    hreg[i];                                                   \
        }                                                                      \
        WG_BARRIER();                                                          \
    } while (0)

    for (int s = 0; s < Tt; s += 2) {
        L1_STEP(s,     0, P1);
        L1_STEP(s + 1, 1, P0);
    }
#undef L1_STEP
}

// ---------------------------------------------------------------------------
// Layer 0 scan (verbatim R14): BC=4, bias-only MFMA init, A-row replication
// (read row lcol&3) -> lane selects acc[quad], no shfl; own-row x-proj.
// ---------------------------------------------------------------------------
__global__ __launch_bounds__(THREADS, 1) void gru_l0(
    const float* __restrict__ x,
    const float* __restrict__ wih_f, const float* __restrict__ whh_f,
    const float* __restrict__ bih_f, const float* __restrict__ bhh_f,
    const float* __restrict__ wih_b, const float* __restrict__ whh_b,
    const float* __restrict__ bih_b, const float* __restrict__ bhh_b,
    unsigned short* __restrict__ y0)
{
    const int tid  = threadIdx.x;
    const int wave = tid >> 6;
    const int lane = tid & 63;
    const int lcol = lane & 15;
    const int quad = lane >> 4;
    const int arow = lcol & 3;        // replicated A row source
    const int dir   = blockIdx.x >> 7;
    const int chunk = blockIdx.x & 127;
    const int b0    = chunk * 4;
    const int c     = 16 * wave + lcol;

    const float* wih = dir ? wih_b : wih_f;
    const float* whh = dir ? whh_b : whh_f;
    const float* bih = dir ? bih_b : bih_f;
    const float* bhh = dir ? bhh_b : bhh_f;

    __shared__ __align__(16) unsigned short lds_h[2][16][136];

    const float brs  = bih[c]       + bhh[c];
    const float bzs  = bih[128 + c] + bhh[128 + c];
    const float bnxs = bih[256 + c];
    const float bnh  = bhh[256 + c];

    float wr[4], wz[4], wn[4];
#pragma unroll
    for (int f = 0; f < 4; ++f) {
        wr[f] = wih[(c)       * 4 + f];
        wz[f] = wih[(128 + c) * 4 + f];
        wn[f] = wih[(256 + c) * 4 + f];
    }

    s16x8 bh[3][4];
#pragma unroll
    for (int p = 0; p < 3; ++p) {
        const int nrow = p * 128 + c;
#pragma unroll
        for (int kk = 0; kk < 4; ++kk) {
            const float* src = &whh[(size_t)nrow * 128 + kk * 32 + quad * 8];
            s16x8 f;
#pragma unroll
            for (int j = 0; j < 8; ++j) f[j] = (short)f2bf(src[j]);
            bh[p][kk] = f;
        }
    }

    auto loadX = [&](float4& X, int t) {
        X = *(const float4*)&x[((size_t)(b0 + quad) * Tt + t) * 4];
    };
    float4 X0, X1;
    loadX(X0, dir ? 511 : 0);
    loadX(X1, dir ? 510 : 1);

    float hmine = 0.f;   // this lane's h element: (row=quad, col=c)
    for (int idx = tid; idx < 2 * 16 * 136; idx += THREADS)
        ((unsigned short*)lds_h)[idx] = 0;
    __syncthreads();

    const int orow = tid >> 7;        // y0 store: row 0..3
    const int ocol = tid & 127;       // col 0..127

#define L0_STEP(S, PAR, XC)                                                    \
    do {                                                                       \
        const int t = dir ? (511 - (S)) : (S);                                 \
        const s16x8 a0 = *(const s16x8*)&lds_h[PAR][arow][0  + quad * 8];      \
        const s16x8 a1 = *(const s16x8*)&lds_h[PAR][arow][32 + quad * 8];      \
        const s16x8 a2 = *(const s16x8*)&lds_h[PAR][arow][64 + quad * 8];      \
        const s16x8 a3 = *(const s16x8*)&lds_h[PAR][arow][96 + quad * 8];      \
        f32x4 accr  = {brs, brs, brs, brs};                                    \
        f32x4 accz  = {bzs, bzs, bzs, bzs};                                    \
        f32x4 acchn = {bnh, bnh, bnh, bnh};                                    \
        accr = MF(a0, bh[0][0], accr); accz = MF(a0, bh[1][0], accz);          \
        acchn = MF(a0, bh[2][0], acchn);                                       \
        accr = MF(a1, bh[0][1], accr); accz = MF(a1, bh[1][1], accz);          \
        acchn = MF(a1, bh[2][1], acchn);                                       \
        accr = MF(a2, bh[0][2], accr); accz = MF(a2, bh[1][2], accz);          \
        acchn = MF(a2, bh[2][2], acchn);                                       \
        accr = MF(a3, bh[0][3], accr); accz = MF(a3, bh[1][3], accz);          \
        acchn = MF(a3, bh[2][3], acchn);                                       \
        const float xr = XC.x * wr[0] + XC.y * wr[1]                           \
                       + XC.z * wr[2] + XC.w * wr[3];                          \
        const float xz = XC.x * wz[0] + XC.y * wz[1]                           \
                       + XC.z * wz[2] + XC.w * wz[3];                          \
        const float xn = bnxs + XC.x * wn[0] + XC.y * wn[1]                    \
                       + XC.z * wn[2] + XC.w * wn[3];                          \
        const float pr = quad == 0 ? accr[0] : quad == 1 ? accr[1]             \
                       : quad == 2 ? accr[2] : accr[3];                        \
        const float pz = quad == 0 ? accz[0] : quad == 1 ? accz[1]             \
                       : quad == 2 ? accz[2] : accz[3];                        \
        const float ph = quad == 0 ? acchn[0] : quad == 1 ? acchn[1]           \
                       : quad == 2 ? acchn[2] : acchn[3];                      \
        {                                                                      \
            const float r = fsig(pr + xr);                                     \
            const float z = fsig(pz + xz);                                     \
            const float n = ftanh(xn + r * ph);                                \
            hmine = (1.0f - z) * n + z * hmine;                                \
            lds_h[PAR ^ 1][quad][c] = f2bf(hmine);                             \
        }                                                                      \
        if ((S) < 510) {                                                       \
            loadX(XC, dir ? (511 - ((S) + 2)) : ((S) + 2));                    \
        }                                                                      \
        WG_BARRIER();                                                          \
        {                                                                      \
            y0[((size_t)t * Bb + b0 + orow) * 256 + dir * 128 + ocol] =        \
                lds_h[PAR ^ 1][orow][ocol];                                    \
        }                                                                      \
    } while (0)

    for (int s = 0; s < Tt; s += 2) {
        L0_STEP(s,     0, X0);
        L0_STEP(s + 1, 1, X1);
    }
#undef L0_STEP
}

// ---------------------------------------------------------------------------
// FC head: out = relu(finals @ fc1^T + b1) @ fc2^T + b2   [512,256]->[512,2]
// ---------------------------------------------------------------------------
__global__ __launch_bounds__(128) void fc_head(
    const float* __restrict__ finals,
    const float* __restrict__ fc1w, const float* __restrict__ fc1b,
    const float* __restrict__ fc2w, const float* __restrict__ fc2b,
    float* __restrict__ out)
{
    __shared__ float s_in[256];
    __shared__ float s_h1[128];
    const int b = blockIdx.x, tid = threadIdx.x;
    s_in[tid]       = finals[(size_t)b * 256 + tid];
    s_in[tid + 128] = finals[(size_t)b * 256 + 128 + tid];
    __syncthreads();
    float acc = fc1b[tid];
    const float* wrow = &fc1w[tid * 256];
#pragma unroll 8
    for (int i = 0; i < 256; ++i) acc += s_in[i] * wrow[i];
    s_h1[tid] = fmaxf(acc, 0.0f);
    __syncthreads();
    if (tid < 2) {
        float a = fc2b[tid];
        const float* w2 = &fc2w[tid * 128];
#pragma unroll 8
        for (int i = 0; i < 128; ++i) a += s_h1[i] * w2[i];
        out[b * 2 + tid] = a;
    }
}

extern "C" void kernel_launch(void* const* d_in, const int* in_sizes, int n_in,
                              void* d_out, int out_size, void* d_ws, size_t ws_size,
                              hipStream_t stream) {
    const float* x      = (const float*)d_in[0];
    const float* wih0f  = (const float*)d_in[1];
    const float* whh0f  = (const float*)d_in[2];
    const float* bih0f  = (const float*)d_in[3];
    const float* bhh0f  = (const float*)d_in[4];
    const float* wih0b  = (const float*)d_in[5];
    const float* whh0b  = (const float*)d_in[6];
    const float* bih0b  = (const float*)d_in[7];
    const float* bhh0b  = (const float*)d_in[8];
    const float* wih1f  = (const float*)d_in[9];
    const float* whh1f  = (const float*)d_in[10];
    const float* bih1f  = (const float*)d_in[11];
    const float* bhh1f  = (const float*)d_in[12];
    const float* wih1b  = (const float*)d_in[13];
    const float* whh1b  = (const float*)d_in[14];
    const float* bih1b  = (const float*)d_in[15];
    const float* bhh1b  = (const float*)d_in[16];
    const float* fc1w   = (const float*)d_in[17];
    const float* fc1b   = (const float*)d_in[18];
    const float* fc2w   = (const float*)d_in[19];
    const float* fc2b   = (const float*)d_in[20];

    const size_t Y0SZ = 134217728ull;   // y0 bf16 [512][512][256]
    const size_t HSSZ = 524288ull;      // hstate/finals f32 [512][256]
    const size_t WCSZ = 393216ull;      // wcat bf16 [768][256]
    const size_t BCSZ = 3072ull;        // bcat f32 [768]
    const size_t GX_PER_SL = 786432ull; // per sl: 2 dirs * 384 * 512 bf16 * 2B
    const size_t BASE = Y0SZ + HSSZ + WCSZ + BCSZ;

    unsigned short* y0 = (unsigned short*)d_ws;
    float*  hstate = (float*)((char*)d_ws + Y0SZ);
    unsigned short* wcat = (unsigned short*)((char*)d_ws + Y0SZ + HSSZ);
    float*  bcat   = (float*)((char*)d_ws + Y0SZ + HSSZ + WCSZ);
    unsigned short* gx0 = (unsigned short*)((char*)d_ws + BASE);
    float* out = (float*)d_out;

    const int cts[6] = {128, 64, 32, 16, 8, 4};
    int CT = 0, fused = 0;
    for (int i = 0; i < 6; ++i)
        if (BASE + 2ull * cts[i] * GX_PER_SL <= ws_size) { CT = cts[i]; fused = 1; break; }
    if (!CT)
        for (int i = 0; i < 6; ++i)
            if (BASE + (size_t)cts[i] * GX_PER_SL <= ws_size) { CT = cts[i]; break; }

    if (CT > 0) {
        unsigned short* gxb[2];
        gxb[0] = gx0;
        gxb[1] = fused ? (unsigned short*)((char*)gx0 + (size_t)CT * GX_PER_SL) : gx0;

        w_prep<<<dim3(768), dim3(256), 0, stream>>>(wih1f, wih1b, bih1f, bih1b, wcat, bcat);
        gru_l0<<<dim3(256), dim3(THREADS), 0, stream>>>(
            x, wih0f, whh0f, bih0f, bhh0f, wih0b, whh0b, bih0b, bhh0b, y0);
        const int n = Tt / CT;
        if (fused) {
            // prologue: gemm chunk 0 -> buf0
            l1_step<<<dim3(24 * CT), dim3(THREADS), 0, stream>>>(
                y0, wcat, bcat, gxb[0], gxb[0],
                whh1f, bhh1f, whh1b, bhh1b, hstate, CT, 0, 0, 1);
            for (int k = 0; k < n; ++k) {
                const int ng = (k + 1 < n) ? 24 * CT : 0;
                l1_step<<<dim3(64 + ng), dim3(THREADS), 0, stream>>>(
                    y0, wcat, bcat, gxb[k & 1], gxb[(k + 1) & 1],
                    whh1f, bhh1f, whh1b, bhh1b, hstate, CT, k + 1, 64, (k == 0) ? 1 : 0);
            }
        } else {
            for (int k = 0; k < n; ++k) {
                l1_step<<<dim3(24 * CT), dim3(THREADS), 0, stream>>>(
                    y0, wcat, bcat, gxb[0], gxb[0],
                    whh1f, bhh1f, whh1b, bhh1b, hstate, CT, k, 0, 1);
                l1_step<<<dim3(64), dim3(THREADS), 0, stream>>>(
                    y0, wcat, bcat, gxb[0], gxb[0],
                    whh1f, bhh1f, whh1b, bhh1b, hstate, CT, 0, 64, (k == 0) ? 1 : 0);
            }
        }
        fc_head<<<dim3(Bb), dim3(128), 0, stream>>>(hstate, fc1w, fc1b, fc2w, fc2b, out);
    } else {
        float* finals = (float*)((char*)d_ws + Y0SZ);
        gru_l0<<<dim3(256), dim3(THREADS), 0, stream>>>(
            x, wih0f, whh0f, bih0f, bhh0f, wih0b, whh0b, bih0b, bhh0b, y0);
        gru_l1<<<dim3(64), dim3(THREADS), 0, stream>>>(
            y0, wih1f, whh1f, bih1f, bhh1f, wih1b, whh1b, bih1b, bhh1b, finals);
        fc_head<<<dim3(Bb), dim3(128), 0, stream>>>(finals, fc1w, fc1b, fc2w, fc2b, out);
    }
}